// Round 1
// baseline (257.368 us; speedup 1.0000x reference)
//
#include <hip/hip_runtime.h>
#include <hip/hip_bf16.h>

// AttnBlock: GN -> QKV 1x1conv -> attention(n=4096,d=512) -> out-proj -> +x
// Strategy: bf16 MFMA NT-GEMM building block (128x128 tile, global_load_lds
// staging with swizzled source cols, XOR-swizzled ds_read_b128), materialized
// S with in-place row softmax.

typedef __attribute__((ext_vector_type(8))) short short8_t;
typedef __attribute__((ext_vector_type(4))) float f32x4;

__device__ __forceinline__ void gload16(const void* g, void* l) {
  __builtin_amdgcn_global_load_lds(
      (const __attribute__((address_space(1))) void*)g,
      (__attribute__((address_space(3))) void*)l, 16, 0, 0);
}

__device__ __forceinline__ short f2bf_bits(float f) {
  __hip_bfloat16 h = __float2bfloat16(f);
  return *reinterpret_cast<short*>(&h);
}
__device__ __forceinline__ float bfbits2f(short s) {
  union { unsigned int u; float f; } c;
  c.u = ((unsigned int)(unsigned short)s) << 16;
  return c.f;
}

// ---------------------------------------------------------------------------
// NT GEMM: C[m][n] = scale * sum_k A[m][k]*B[n][k] (+bias)(+resid)
// A: [M,K] bf16 row-major, B: [N,K] bf16 row-major. M,N mult of 128, K of 64.
// OUTF: 0 = bf16 out, 1 = f32 out. BIASMODE: 0 none, 1 per-row(m), 2 per-col(n).
// ---------------------------------------------------------------------------
template<int OUTF, int BIASMODE, int RESID>
__global__ __launch_bounds__(256, 2)
void gemm_nt(const __hip_bfloat16* __restrict__ A,
             const __hip_bfloat16* __restrict__ B,
             void* __restrict__ Cv,
             const float* __restrict__ bias,
             const float* __restrict__ resid,
             float scale, int M, int N, int K,
             long long strA, long long strB, long long strC, long long strR)
{
  const int z = blockIdx.z;
  A += (size_t)z * strA;
  B += (size_t)z * strB;

  const int tid = threadIdx.x;
  const int w = tid >> 6, l = tid & 63;
  const int wr = w >> 1, wc = w & 1;
  const int lhi = l >> 4, llo = l & 15;
  const int m0 = blockIdx.x * 128, n0 = blockIdx.y * 128;

  __shared__ char sm[2 * 128 * 64 * 2];  // A tile 16KB + B tile 16KB
  char* sA = sm;
  char* sB = sm + 128 * 64 * 2;

  f32x4 acc[4][4] = {};

  // staging: each global_load_lds writes 64 lanes * 16B = 1KB = 8 rows of 64 bf16.
  // LDS is linear; source column is pre-swizzled so that ds_read applies
  // byte ^= ((row&7)<<4) conflict-free swizzle.
  const int rowInCh = l >> 3;
  const int colOff = 8 * ((l & 7) ^ (rowInCh & 7));

  const __hip_bfloat16* gA = A + (size_t)(m0 + w * 32 + rowInCh) * K + colOff;
  const __hip_bfloat16* gB = B + (size_t)(n0 + w * 32 + rowInCh) * K + colOff;

  const int nkt = K >> 6;
  for (int kt = 0; kt < nkt; ++kt) {
    __syncthreads();
#pragma unroll
    for (int r = 0; r < 4; ++r) {
      const int ch = w * 4 + r;
      gload16(gA + (size_t)(r * 8) * K, sA + ch * 1024);
      gload16(gB + (size_t)(r * 8) * K, sB + ch * 1024);
    }
    gA += 64; gB += 64;
    __syncthreads();  // compiler drains vmcnt before barrier
#pragma unroll
    for (int kk = 0; kk < 2; ++kk) {
      short8_t af[4], bf[4];
#pragma unroll
      for (int m = 0; m < 4; ++m) {
        const int row = wr * 64 + m * 16 + llo;
        const int inner = ((kk * 4 + lhi) ^ (row & 7)) * 16;
        af[m] = *(const short8_t*)(sA + row * 128 + inner);
      }
#pragma unroll
      for (int n = 0; n < 4; ++n) {
        const int row = wc * 64 + n * 16 + llo;
        const int inner = ((kk * 4 + lhi) ^ (row & 7)) * 16;
        bf[n] = *(const short8_t*)(sB + row * 128 + inner);
      }
#pragma unroll
      for (int m = 0; m < 4; ++m)
#pragma unroll
        for (int n = 0; n < 4; ++n)
          acc[m][n] = __builtin_amdgcn_mfma_f32_16x16x32_bf16(af[m], bf[n], acc[m][n], 0, 0, 0);
    }
  }

  // epilogue: C/D layout col=lane&15, row=(lane>>4)*4+reg  [m89-verified]
#pragma unroll
  for (int m = 0; m < 4; ++m) {
#pragma unroll
    for (int r = 0; r < 4; ++r) {
      const int grow = m0 + wr * 64 + m * 16 + lhi * 4 + r;
#pragma unroll
      for (int n = 0; n < 4; ++n) {
        const int gcol = n0 + wc * 64 + n * 16 + llo;
        float v = acc[m][n][r] * scale;
        if (BIASMODE == 1) v += bias[grow];
        if (BIASMODE == 2) v += bias[gcol];
        const size_t idx = (size_t)z * strC + (size_t)grow * N + gcol;
        if (RESID) v += resid[(size_t)z * strR + (size_t)grow * N + gcol];
        if (OUTF == 0) ((__hip_bfloat16*)Cv)[idx] = __float2bfloat16(v);
        else           ((float*)Cv)[idx] = v;
      }
    }
  }
}

// ---------------------------------------------------------------------------
// GroupNorm stats: one block per (group, z). 16 ch * 4096 = 65536 elements.
// ---------------------------------------------------------------------------
__global__ __launch_bounds__(256)
void gn_stats(const float* __restrict__ x, float* __restrict__ stats)
{
  const int g = blockIdx.x, z = blockIdx.y;
  const int tid = threadIdx.x;
  const float* px = x + ((size_t)z * 512 + g * 16) * 4096;
  float s = 0.f, q = 0.f;
  for (int i = tid; i < 16 * 4096; i += 256) {
    float v = px[i];
    s += v; q += v * v;
  }
#pragma unroll
  for (int o = 32; o; o >>= 1) { s += __shfl_xor(s, o); q += __shfl_xor(q, o); }
  __shared__ float rs[4], rq[4];
  if ((tid & 63) == 0) { rs[tid >> 6] = s; rq[tid >> 6] = q; }
  __syncthreads();
  if (tid == 0) {
    s = rs[0] + rs[1] + rs[2] + rs[3];
    q = rq[0] + rq[1] + rq[2] + rq[3];
    const float mean = s * (1.0f / 65536.0f);
    const float var = q * (1.0f / 65536.0f) - mean * mean;
    stats[(z * 32 + g) * 2 + 0] = mean;
    stats[(z * 32 + g) * 2 + 1] = rsqrtf(var + 1e-6f);
  }
}

// ---------------------------------------------------------------------------
// Normalize + transpose: x[z][c][s] f32 -> ht[z][s][c] bf16 (64x64 LDS tiles)
// ---------------------------------------------------------------------------
__global__ __launch_bounds__(256)
void gn_apply_t(const float* __restrict__ x, const float* __restrict__ stats,
                const float* __restrict__ gns, const float* __restrict__ gnb,
                __hip_bfloat16* __restrict__ ht)
{
  const int st = blockIdx.x, ct = blockIdx.y, z = blockIdx.z;
  const int tid = threadIdx.x;
  __shared__ float tile[64][65];
  const float* xb = x + (size_t)z * 512 * 4096;
  const int lane64 = tid & 63, rr = tid >> 6;
#pragma unroll
  for (int pp = 0; pp < 16; ++pp) {
    const int cl = pp * 4 + rr;
    const int c = ct * 64 + cl;
    const int g = c >> 4;
    const float mean = stats[(z * 32 + g) * 2 + 0];
    const float rstd = stats[(z * 32 + g) * 2 + 1];
    const float val = xb[(size_t)c * 4096 + st * 64 + lane64];
    tile[cl][lane64] = (val - mean) * rstd * gns[c] + gnb[c];
  }
  __syncthreads();
  __hip_bfloat16* hb = ht + (size_t)z * 4096 * 512;
#pragma unroll
  for (int pp = 0; pp < 16; ++pp) {
    const int sl = pp * 4 + rr;
    const int s = st * 64 + sl;
    hb[(size_t)s * 512 + ct * 64 + lane64] = __float2bfloat16(tile[lane64][sl]);
  }
}

// ---------------------------------------------------------------------------
// In-place row softmax over 4096 bf16 (S already scaled). 256 thr x 16 elems.
// ---------------------------------------------------------------------------
__global__ __launch_bounds__(256)
void softmax_rows(__hip_bfloat16* __restrict__ S, long long strZ)
{
  const int row = blockIdx.x, z = blockIdx.y;
  __hip_bfloat16* p = S + (size_t)z * strZ + (size_t)row * 4096;
  const int tid = threadIdx.x;
  short8_t a = *(const short8_t*)(p + tid * 16);
  short8_t b = *(const short8_t*)(p + tid * 16 + 8);
  float v[16];
#pragma unroll
  for (int i = 0; i < 8; ++i) { v[i] = bfbits2f(a[i]); v[8 + i] = bfbits2f(b[i]); }
  float m = v[0];
#pragma unroll
  for (int i = 1; i < 16; ++i) m = fmaxf(m, v[i]);
#pragma unroll
  for (int o = 32; o; o >>= 1) m = fmaxf(m, __shfl_xor(m, o));
  __shared__ float red[8];
  if ((tid & 63) == 0) red[tid >> 6] = m;
  __syncthreads();
  m = fmaxf(fmaxf(red[0], red[1]), fmaxf(red[2], red[3]));
  float s = 0.f;
#pragma unroll
  for (int i = 0; i < 16; ++i) { v[i] = exp2f((v[i] - m) * 1.44269504f); s += v[i]; }
#pragma unroll
  for (int o = 32; o; o >>= 1) s += __shfl_xor(s, o);
  __syncthreads();  // everyone done reading red[0..3]
  if ((tid & 63) == 0) red[4 + (tid >> 6)] = s;
  __syncthreads();
  s = red[4] + red[5] + red[6] + red[7];
  const float inv = 1.f / s;
#pragma unroll
  for (int i = 0; i < 8; ++i) { a[i] = f2bf_bits(v[i] * inv); b[i] = f2bf_bits(v[8 + i] * inv); }
  *(short8_t*)(p + tid * 16) = a;
  *(short8_t*)(p + tid * 16 + 8) = b;
}

__global__ __launch_bounds__(256)
void f32_to_bf16_k(const float* __restrict__ in, __hip_bfloat16* __restrict__ out, int n)
{
  const int i = blockIdx.x * 256 + threadIdx.x;
  if (i < n) out[i] = __float2bfloat16(in[i]);
}

// ---------------------------------------------------------------------------
extern "C" void kernel_launch(void* const* d_in, const int* in_sizes, int n_in,
                              void* d_out, int out_size, void* d_ws, size_t ws_size,
                              hipStream_t stream)
{
  const float* x   = (const float*)d_in[0];
  const float* gns = (const float*)d_in[1];
  const float* gnb = (const float*)d_in[2];
  const float* wq  = (const float*)d_in[3];
  const float* bq  = (const float*)d_in[4];
  const float* wk  = (const float*)d_in[5];
  const float* bk  = (const float*)d_in[6];
  const float* wv  = (const float*)d_in[7];
  const float* bv  = (const float*)d_in[8];
  const float* wo  = (const float*)d_in[9];
  const float* bo  = (const float*)d_in[10];
  float* out = (float*)d_out;

  const int WB = 512 * 512;                 // weight elements
  const long long HT = 4096LL * 512;        // per-batch stride for [4096,512]/[512,4096]
  const long long SS = 4096LL * 4096;       // S stride
  const size_t CHW = (size_t)512 * 4096;

  char* p = (char*)d_ws;
  auto take = [&](size_t b) { char* r = p; p += (b + 255) & ~(size_t)255; return r; };

  __hip_bfloat16* wbf = (__hip_bfloat16*)take((size_t)4 * WB * 2);  // wq,wk,wv,wo bf16
  float* stats = (float*)take(1024);

  const size_t fixed = (size_t)(p - (char*)d_ws);
  const size_t per_batch = 5 * ((size_t)HT * 2) + (size_t)SS * 2;   // ~52MB
  const int P = (ws_size >= fixed + 2 * per_batch + 65536) ? 2 : 1;

  __hip_bfloat16* ht   = (__hip_bfloat16*)take((size_t)P * HT * 2);
  __hip_bfloat16* qt   = (__hip_bfloat16*)take((size_t)P * HT * 2);
  __hip_bfloat16* kt   = (__hip_bfloat16*)take((size_t)P * HT * 2);
  __hip_bfloat16* vb   = (__hip_bfloat16*)take((size_t)P * HT * 2);
  __hip_bfloat16* ot   = (__hip_bfloat16*)take((size_t)P * HT * 2);
  __hip_bfloat16* sbuf = (__hip_bfloat16*)take((size_t)P * SS * 2);

  f32_to_bf16_k<<<1024, 256, 0, stream>>>(wq, wbf + 0 * WB, WB);
  f32_to_bf16_k<<<1024, 256, 0, stream>>>(wk, wbf + 1 * WB, WB);
  f32_to_bf16_k<<<1024, 256, 0, stream>>>(wv, wbf + 2 * WB, WB);
  f32_to_bf16_k<<<1024, 256, 0, stream>>>(wo, wbf + 3 * WB, WB);

  const float SC = 0.04419417382415922f;  // 512^-0.5

  for (int b0 = 0; b0 < 2; b0 += P) {
    const float* xb = x + (size_t)b0 * CHW;
    float* ob = out + (size_t)b0 * CHW;

    gn_stats<<<dim3(32, P), 256, 0, stream>>>(xb, stats);
    gn_apply_t<<<dim3(64, 8, P), 256, 0, stream>>>(xb, stats, gns, gnb, ht);

    // Qt[s][o] = ht . wq^T + bq   (bias per col)
    gemm_nt<0, 2, 0><<<dim3(32, 4, P), 256, 0, stream>>>(
        ht, wbf + 0 * WB, qt, bq, nullptr, 1.f, 4096, 512, 512, HT, 0, HT, 0);
    gemm_nt<0, 2, 0><<<dim3(32, 4, P), 256, 0, stream>>>(
        ht, wbf + 1 * WB, kt, bk, nullptr, 1.f, 4096, 512, 512, HT, 0, HT, 0);
    // V[c][s] = wv . ht^T + bv    (bias per row)
    gemm_nt<0, 1, 0><<<dim3(4, 32, P), 256, 0, stream>>>(
        wbf + 2 * WB, ht, vb, bv, nullptr, 1.f, 512, 4096, 512, 0, HT, HT, 0);
    // S[i][j] = (qt . kt^T) * scale
    gemm_nt<0, 0, 0><<<dim3(32, 32, P), 256, 0, stream>>>(
        qt, kt, sbuf, nullptr, nullptr, SC, 4096, 4096, 512, HT, HT, SS, 0);
    softmax_rows<<<dim3(4096, P), 256, 0, stream>>>(sbuf, SS);
    // Ot[i][c] = P . V   (A=P [4096,4096], B=V [512,4096], both contiguous-K)
    gemm_nt<0, 0, 0><<<dim3(32, 4, P), 256, 0, stream>>>(
        sbuf, vb, ot, nullptr, nullptr, 1.f, 4096, 512, 4096, SS, HT, HT, 0);
    // out[o][s] = wo . Ot^T + bo + x
    gemm_nt<1, 1, 1><<<dim3(4, 32, P), 256, 0, stream>>>(
        wbf + 3 * WB, ot, ob, bo, xb, 1.f, 512, 4096, 512, 0, HT, (long long)CHW, (long long)CHW);
  }
}

// Round 2
// 195.055 us; speedup vs baseline: 1.3195x; 1.3195x over previous
//
#include <hip/hip_runtime.h>
#include <hip/hip_bf16.h>

// AttnBlock: GN -> QKV 1x1conv -> attention(n=4096,d=512) -> out-proj -> +x
// R2: two-stage GN stats (was 2x100us latency-bound), z-batched skinny GEMMs
// where workspace allows, fused weight cast.

typedef __attribute__((ext_vector_type(8))) short short8_t;
typedef __attribute__((ext_vector_type(4))) short short4_t;
typedef __attribute__((ext_vector_type(4))) float f32x4;

__device__ __forceinline__ void gload16(const void* g, void* l) {
  __builtin_amdgcn_global_load_lds(
      (const __attribute__((address_space(1))) void*)g,
      (__attribute__((address_space(3))) void*)l, 16, 0, 0);
}

__device__ __forceinline__ short f2bf_bits(float f) {
  __hip_bfloat16 h = __float2bfloat16(f);
  return *reinterpret_cast<short*>(&h);
}
__device__ __forceinline__ float bfbits2f(short s) {
  union { unsigned int u; float f; } c;
  c.u = ((unsigned int)(unsigned short)s) << 16;
  return c.f;
}

// ---------------------------------------------------------------------------
// NT GEMM: C[m][n] = scale * sum_k A[m][k]*B[n][k] (+bias)(+resid)
// A: [M,K] bf16 row-major, B: [N,K] bf16 row-major. M,N mult of 128, K of 64.
// OUTF: 0 = bf16 out, 1 = f32 out. BIASMODE: 0 none, 1 per-row(m), 2 per-col(n).
// ---------------------------------------------------------------------------
template<int OUTF, int BIASMODE, int RESID>
__global__ __launch_bounds__(256, 2)
void gemm_nt(const __hip_bfloat16* __restrict__ A,
             const __hip_bfloat16* __restrict__ B,
             void* __restrict__ Cv,
             const float* __restrict__ bias,
             const float* __restrict__ resid,
             float scale, int M, int N, int K,
             long long strA, long long strB, long long strC, long long strR)
{
  const int z = blockIdx.z;
  A += (size_t)z * strA;
  B += (size_t)z * strB;

  const int tid = threadIdx.x;
  const int w = tid >> 6, l = tid & 63;
  const int wr = w >> 1, wc = w & 1;
  const int lhi = l >> 4, llo = l & 15;
  const int m0 = blockIdx.x * 128, n0 = blockIdx.y * 128;

  __shared__ char sm[2 * 128 * 64 * 2];  // A tile 16KB + B tile 16KB
  char* sA = sm;
  char* sB = sm + 128 * 64 * 2;

  f32x4 acc[4][4] = {};

  // staging: each global_load_lds writes 64 lanes * 16B = 1KB = 8 rows of 64 bf16.
  // LDS linear; source column pre-swizzled so ds_read uses byte^((row&7)<<4).
  const int rowInCh = l >> 3;
  const int colOff = 8 * ((l & 7) ^ (rowInCh & 7));

  const __hip_bfloat16* gA = A + (size_t)(m0 + w * 32 + rowInCh) * K + colOff;
  const __hip_bfloat16* gB = B + (size_t)(n0 + w * 32 + rowInCh) * K + colOff;

  const int nkt = K >> 6;
  for (int kt = 0; kt < nkt; ++kt) {
    __syncthreads();
#pragma unroll
    for (int r = 0; r < 4; ++r) {
      const int ch = w * 4 + r;
      gload16(gA + (size_t)(r * 8) * K, sA + ch * 1024);
      gload16(gB + (size_t)(r * 8) * K, sB + ch * 1024);
    }
    gA += 64; gB += 64;
    __syncthreads();
#pragma unroll
    for (int kk = 0; kk < 2; ++kk) {
      short8_t af[4], bf[4];
#pragma unroll
      for (int m = 0; m < 4; ++m) {
        const int row = wr * 64 + m * 16 + llo;
        const int inner = ((kk * 4 + lhi) ^ (row & 7)) * 16;
        af[m] = *(const short8_t*)(sA + row * 128 + inner);
      }
#pragma unroll
      for (int n = 0; n < 4; ++n) {
        const int row = wc * 64 + n * 16 + llo;
        const int inner = ((kk * 4 + lhi) ^ (row & 7)) * 16;
        bf[n] = *(const short8_t*)(sB + row * 128 + inner);
      }
#pragma unroll
      for (int m = 0; m < 4; ++m)
#pragma unroll
        for (int n = 0; n < 4; ++n)
          acc[m][n] = __builtin_amdgcn_mfma_f32_16x16x32_bf16(af[m], bf[n], acc[m][n], 0, 0, 0);
    }
  }

  // epilogue: C/D layout col=lane&15, row=(lane>>4)*4+reg  [m89-verified]
#pragma unroll
  for (int m = 0; m < 4; ++m) {
#pragma unroll
    for (int r = 0; r < 4; ++r) {
      const int grow = m0 + wr * 64 + m * 16 + lhi * 4 + r;
#pragma unroll
      for (int n = 0; n < 4; ++n) {
        const int gcol = n0 + wc * 64 + n * 16 + llo;
        float v = acc[m][n][r] * scale;
        if (BIASMODE == 1) v += bias[grow];
        if (BIASMODE == 2) v += bias[gcol];
        const size_t idx = (size_t)z * strC + (size_t)grow * N + gcol;
        if (RESID) v += resid[(size_t)z * strR + (size_t)grow * N + gcol];
        if (OUTF == 0) ((__hip_bfloat16*)Cv)[idx] = __float2bfloat16(v);
        else           ((float*)Cv)[idx] = v;
      }
    }
  }
}

// ---------------------------------------------------------------------------
// GN stats stage A: partial sums. grid (32 groups, 16 slices, 2 z), 256 thr.
// Each block: 4096 contiguous floats (16 float/thread, float4 loads).
// ---------------------------------------------------------------------------
__global__ __launch_bounds__(256)
void gn_partial(const float* __restrict__ x, float* __restrict__ part)
{
  const int g = blockIdx.x, sl = blockIdx.y, z = blockIdx.z;
  const int tid = threadIdx.x;
  const float* xf = x + (size_t)z * 512 * 4096 + (size_t)g * 16 * 4096 + (size_t)sl * 4096;
  const float4* px = reinterpret_cast<const float4*>(xf);
  float s = 0.f, q = 0.f;
#pragma unroll
  for (int i = 0; i < 4; ++i) {
    float4 v = px[tid + i * 256];
    s += v.x + v.y + v.z + v.w;
    q += v.x * v.x + v.y * v.y + v.z * v.z + v.w * v.w;
  }
#pragma unroll
  for (int o = 32; o; o >>= 1) { s += __shfl_xor(s, o); q += __shfl_xor(q, o); }
  __shared__ float rs[4], rq[4];
  if ((tid & 63) == 0) { rs[tid >> 6] = s; rq[tid >> 6] = q; }
  __syncthreads();
  if (tid == 0) {
    s = rs[0] + rs[1] + rs[2] + rs[3];
    q = rq[0] + rq[1] + rq[2] + rq[3];
    part[(((size_t)z * 32 + g) * 16 + sl) * 2 + 0] = s;
    part[(((size_t)z * 32 + g) * 16 + sl) * 2 + 1] = q;
  }
}

// Stage B: 64 (z,group) pairs, one thread each.
__global__ __launch_bounds__(64)
void gn_finalize(const float* __restrict__ part, float* __restrict__ stats, int n)
{
  const int i = threadIdx.x;
  if (i >= n) return;
  float s = 0.f, q = 0.f;
#pragma unroll
  for (int sl = 0; sl < 16; ++sl) {
    s += part[(i * 16 + sl) * 2 + 0];
    q += part[(i * 16 + sl) * 2 + 1];
  }
  const float mean = s * (1.0f / 65536.0f);
  const float var = q * (1.0f / 65536.0f) - mean * mean;
  stats[i * 2 + 0] = mean;
  stats[i * 2 + 1] = rsqrtf(var + 1e-6f);
}

// ---------------------------------------------------------------------------
// Normalize + transpose: x[z][c][s] f32 -> ht[z][s][c] bf16 (64x64 LDS tiles)
// ---------------------------------------------------------------------------
__global__ __launch_bounds__(256)
void gn_apply_t(const float* __restrict__ x, const float* __restrict__ stats,
                const float* __restrict__ gns, const float* __restrict__ gnb,
                __hip_bfloat16* __restrict__ ht)
{
  const int st = blockIdx.x, ct = blockIdx.y, z = blockIdx.z;
  const int tid = threadIdx.x;
  __shared__ float tile[64][65];
  const float* xb = x + (size_t)z * 512 * 4096;
  const int lane64 = tid & 63, rr = tid >> 6;
#pragma unroll
  for (int pp = 0; pp < 16; ++pp) {
    const int cl = pp * 4 + rr;
    const int c = ct * 64 + cl;
    const int g = c >> 4;
    const float mean = stats[(z * 32 + g) * 2 + 0];
    const float rstd = stats[(z * 32 + g) * 2 + 1];
    const float val = xb[(size_t)c * 4096 + st * 64 + lane64];
    tile[cl][lane64] = (val - mean) * rstd * gns[c] + gnb[c];
  }
  __syncthreads();
  __hip_bfloat16* hb = ht + (size_t)z * 4096 * 512;
#pragma unroll
  for (int pp = 0; pp < 16; ++pp) {
    const int sl = pp * 4 + rr;
    const int s = st * 64 + sl;
    hb[(size_t)s * 512 + ct * 64 + lane64] = __float2bfloat16(tile[lane64][sl]);
  }
}

// ---------------------------------------------------------------------------
// In-place row softmax over 4096 bf16. 256 thr x 16 elems.
// ---------------------------------------------------------------------------
__global__ __launch_bounds__(256)
void softmax_rows(__hip_bfloat16* __restrict__ S, long long strZ)
{
  const int row = blockIdx.x, z = blockIdx.y;
  __hip_bfloat16* p = S + (size_t)z * strZ + (size_t)row * 4096;
  const int tid = threadIdx.x;
  short8_t a = *(const short8_t*)(p + tid * 16);
  short8_t b = *(const short8_t*)(p + tid * 16 + 8);
  float v[16];
#pragma unroll
  for (int i = 0; i < 8; ++i) { v[i] = bfbits2f(a[i]); v[8 + i] = bfbits2f(b[i]); }
  float m = v[0];
#pragma unroll
  for (int i = 1; i < 16; ++i) m = fmaxf(m, v[i]);
#pragma unroll
  for (int o = 32; o; o >>= 1) m = fmaxf(m, __shfl_xor(m, o));
  __shared__ float red[8];
  if ((tid & 63) == 0) red[tid >> 6] = m;
  __syncthreads();
  m = fmaxf(fmaxf(red[0], red[1]), fmaxf(red[2], red[3]));
  float s = 0.f;
#pragma unroll
  for (int i = 0; i < 16; ++i) { v[i] = exp2f((v[i] - m) * 1.44269504f); s += v[i]; }
#pragma unroll
  for (int o = 32; o; o >>= 1) s += __shfl_xor(s, o);
  __syncthreads();
  if ((tid & 63) == 0) red[4 + (tid >> 6)] = s;
  __syncthreads();
  s = red[4] + red[5] + red[6] + red[7];
  const float inv = 1.f / s;
#pragma unroll
  for (int i = 0; i < 8; ++i) { a[i] = f2bf_bits(v[i] * inv); b[i] = f2bf_bits(v[8 + i] * inv); }
  *(short8_t*)(p + tid * 16) = a;
  *(short8_t*)(p + tid * 16 + 8) = b;
}

// All four weights cast in one launch. grid 256x256 = 65536 float4/weight.
__global__ __launch_bounds__(256)
void cast_weights(const float* __restrict__ w0, const float* __restrict__ w1,
                  const float* __restrict__ w2, const float* __restrict__ w3,
                  __hip_bfloat16* __restrict__ out)
{
  const int i = blockIdx.x * 256 + threadIdx.x;  // float4 index, < 65536
  const float* srcs[4] = {w0, w1, w2, w3};
#pragma unroll
  for (int j = 0; j < 4; ++j) {
    float4 v = reinterpret_cast<const float4*>(srcs[j])[i];
    short4_t o;
    o[0] = f2bf_bits(v.x); o[1] = f2bf_bits(v.y);
    o[2] = f2bf_bits(v.z); o[3] = f2bf_bits(v.w);
    *reinterpret_cast<short4_t*>((short*)out + (size_t)j * 512 * 512 + (size_t)i * 4) = o;
  }
}

// ---------------------------------------------------------------------------
extern "C" void kernel_launch(void* const* d_in, const int* in_sizes, int n_in,
                              void* d_out, int out_size, void* d_ws, size_t ws_size,
                              hipStream_t stream)
{
  const float* x   = (const float*)d_in[0];
  const float* gns = (const float*)d_in[1];
  const float* gnb = (const float*)d_in[2];
  const float* wq  = (const float*)d_in[3];
  const float* bq  = (const float*)d_in[4];
  const float* wk  = (const float*)d_in[5];
  const float* bk  = (const float*)d_in[6];
  const float* wv  = (const float*)d_in[7];
  const float* bv  = (const float*)d_in[8];
  const float* wo  = (const float*)d_in[9];
  const float* bo  = (const float*)d_in[10];
  float* out = (float*)d_out;

  const int WB = 512 * 512;
  const long long HT = 4096LL * 512;
  const long long SS = 4096LL * 4096;
  const size_t CHW = (size_t)512 * 4096;
  const size_t HTB = (size_t)HT * 2;   // 4 MB
  const size_t SSB = (size_t)SS * 2;   // 32 MB

  char* base = (char*)d_ws;
  size_t off = 0;
  auto alloc = [&](size_t b) { void* r = base + off; off = (off + b + 255) & ~(size_t)255; return r; };

  __hip_bfloat16* wbf = (__hip_bfloat16*)alloc((size_t)4 * WB * 2);
  float* part  = (float*)alloc(2 * 32 * 16 * 2 * sizeof(float));
  float* stats = (float*)alloc(2 * 32 * 2 * sizeof(float));
  const size_t fixed = off;

  // MODE2: everything z-batched (ht2,qt2,kt2,vb2,S2; ot aliases ht)
  // MODE1: z-batched proj GEMMs, shared single S
  // MODE0: fully per-batch
  const size_t need_full = fixed + 4 * 2 * HTB + 2 * SSB;
  const size_t need_mid  = fixed + 4 * 2 * HTB + 1 * SSB;
  const int MODE = (ws_size >= need_full) ? 2 : (ws_size >= need_mid) ? 1 : 0;
  const int NZ = (MODE >= 1) ? 2 : 1;

  __hip_bfloat16* ht   = (__hip_bfloat16*)alloc((size_t)NZ * HTB);
  __hip_bfloat16* qt   = (__hip_bfloat16*)alloc((size_t)NZ * HTB);
  __hip_bfloat16* kt   = (__hip_bfloat16*)alloc((size_t)NZ * HTB);
  __hip_bfloat16* vb   = (__hip_bfloat16*)alloc((size_t)NZ * HTB);
  __hip_bfloat16* sbuf = (__hip_bfloat16*)alloc((size_t)((MODE == 2) ? 2 : 1) * SSB);
  __hip_bfloat16* ot   = ht;  // ht dead after V GEMM

  const float SC = 0.04419417382415922f;  // 512^-0.5

  cast_weights<<<256, 256, 0, stream>>>(wq, wk, wv, wo, wbf);
  gn_partial<<<dim3(32, 16, 2), 256, 0, stream>>>(x, part);
  gn_finalize<<<1, 64, 0, stream>>>(part, stats, 64);

  if (MODE >= 1) {
    gn_apply_t<<<dim3(64, 8, 2), 256, 0, stream>>>(x, stats, gns, gnb, ht);
    gemm_nt<0, 2, 0><<<dim3(32, 4, 2), 256, 0, stream>>>(
        ht, wbf + 0 * WB, qt, bq, nullptr, 1.f, 4096, 512, 512, HT, 0, HT, 0);
    gemm_nt<0, 2, 0><<<dim3(32, 4, 2), 256, 0, stream>>>(
        ht, wbf + 1 * WB, kt, bk, nullptr, 1.f, 4096, 512, 512, HT, 0, HT, 0);
    gemm_nt<0, 1, 0><<<dim3(4, 32, 2), 256, 0, stream>>>(
        wbf + 2 * WB, ht, vb, bv, nullptr, 1.f, 512, 4096, 512, 0, HT, HT, 0);
    if (MODE == 2) {
      gemm_nt<0, 0, 0><<<dim3(32, 32, 2), 256, 0, stream>>>(
          qt, kt, sbuf, nullptr, nullptr, SC, 4096, 4096, 512, HT, HT, SS, 0);
      softmax_rows<<<dim3(4096, 2), 256, 0, stream>>>(sbuf, SS);
      gemm_nt<0, 0, 0><<<dim3(32, 4, 2), 256, 0, stream>>>(
          sbuf, vb, ot, nullptr, nullptr, 1.f, 4096, 512, 4096, SS, HT, HT, 0);
    } else {
      for (int z = 0; z < 2; ++z) {
        gemm_nt<0, 0, 0><<<dim3(32, 32, 1), 256, 0, stream>>>(
            qt + (size_t)z * HT, kt + (size_t)z * HT, sbuf, nullptr, nullptr,
            SC, 4096, 4096, 512, 0, 0, 0, 0);
        softmax_rows<<<dim3(4096, 1), 256, 0, stream>>>(sbuf, 0);
        gemm_nt<0, 0, 0><<<dim3(32, 4, 1), 256, 0, stream>>>(
            sbuf, vb + (size_t)z * HT, ot + (size_t)z * HT, nullptr, nullptr,
            1.f, 4096, 512, 4096, 0, 0, 0, 0);
      }
    }
    gemm_nt<1, 1, 1><<<dim3(4, 32, 2), 256, 0, stream>>>(
        wbf + 3 * WB, ot, out, bo, x, 1.f, 512, 4096, 512, 0, HT, (long long)CHW, (long long)CHW);
  } else {
    for (int b0 = 0; b0 < 2; ++b0) {
      const float* xb = x + (size_t)b0 * CHW;
      float* ob = out + (size_t)b0 * CHW;
      gn_apply_t<<<dim3(64, 8, 1), 256, 0, stream>>>(xb, stats + b0 * 64, gns, gnb, ht);
      gemm_nt<0, 2, 0><<<dim3(32, 4, 1), 256, 0, stream>>>(
          ht, wbf + 0 * WB, qt, bq, nullptr, 1.f, 4096, 512, 512, 0, 0, 0, 0);
      gemm_nt<0, 2, 0><<<dim3(32, 4, 1), 256, 0, stream>>>(
          ht, wbf + 1 * WB, kt, bk, nullptr, 1.f, 4096, 512, 512, 0, 0, 0, 0);
      gemm_nt<0, 1, 0><<<dim3(4, 32, 1), 256, 0, stream>>>(
          wbf + 2 * WB, ht, vb, bv, nullptr, 1.f, 512, 4096, 512, 0, 0, 0, 0);
      gemm_nt<0, 0, 0><<<dim3(32, 32, 1), 256, 0, stream>>>(
          qt, kt, sbuf, nullptr, nullptr, SC, 4096, 4096, 512, 0, 0, 0, 0);
      softmax_rows<<<dim3(4096, 1), 256, 0, stream>>>(sbuf, 0);
      gemm_nt<0, 0, 0><<<dim3(32, 4, 1), 256, 0, stream>>>(
          sbuf, vb, ot, nullptr, nullptr, 1.f, 4096, 512, 4096, 0, 0, 0, 0);
      gemm_nt<1, 1, 1><<<dim3(4, 32, 1), 256, 0, stream>>>(
          wbf + 3 * WB, ot, ob, bo, xb, 1.f, 512, 4096, 512, 0, 0,
          (long long)CHW, (long long)CHW);
    }
  }
}

// Round 3
// 177.772 us; speedup vs baseline: 1.4477x; 1.0972x over previous
//
#include <hip/hip_runtime.h>
#include <hip/hip_bf16.h>

// AttnBlock: GN -> QKV 1x1conv -> attention(n=4096,d=512) -> out-proj -> +x
// R3: (1) fold wv and wo into WVO = wo.wv (softmax rows sum to 1) -> V GEMM
// and out-proj GEMM eliminated, PV writes d_out directly with bias+residual.
// (2) double-buffered global_load_lds prefetch pipeline for low-occupancy
// GEMMs. (3) Q,K fused into one N=1024 GEMM.

typedef __attribute__((ext_vector_type(8))) short short8_t;
typedef __attribute__((ext_vector_type(4))) short short4_t;
typedef __attribute__((ext_vector_type(4))) float f32x4;

__device__ __forceinline__ void gload16(const void* g, void* l) {
  __builtin_amdgcn_global_load_lds(
      (const __attribute__((address_space(1))) void*)g,
      (__attribute__((address_space(3))) void*)l, 16, 0, 0);
}

__device__ __forceinline__ short f2bf_bits(float f) {
  __hip_bfloat16 h = __float2bfloat16(f);
  return *reinterpret_cast<short*>(&h);
}
__device__ __forceinline__ float bfbits2f(short s) {
  union { unsigned int u; float f; } c;
  c.u = ((unsigned int)(unsigned short)s) << 16;
  return c.f;
}

// ---------------------------------------------------------------------------
// NT GEMM: C[m][n] = scale * sum_k A[m][k]*B[n][k] (+bias)(+resid)
// A rows at lda, B rows at ldb (both bf16, K-contiguous). M,N mult 128, K of 64.
// OUTF: 0 bf16 out, 1 f32 out. BIASMODE: 0 none, 1 per-row(m), 2 per-col(n).
// PIPE: 1 = double-buffered prefetch (64KB LDS), 0 = serial (32KB LDS).
// ---------------------------------------------------------------------------
template<int OUTF, int BIASMODE, int RESID, int PIPE>
__global__ __launch_bounds__(256, 2)
void gemm_nt(const __hip_bfloat16* __restrict__ A,
             const __hip_bfloat16* __restrict__ B,
             void* __restrict__ Cv,
             const float* __restrict__ bias,
             const float* __restrict__ resid,
             float scale, int M, int N, int K,
             int lda, int ldb, int ldc,
             long long strA, long long strB, long long strC, long long strR)
{
  const int z = blockIdx.z;
  A += (size_t)z * strA;
  B += (size_t)z * strB;

  const int tid = threadIdx.x;
  const int w = tid >> 6, l = tid & 63;
  const int wr = w >> 1, wc = w & 1;
  const int lhi = l >> 4, llo = l & 15;
  const int m0 = blockIdx.x * 128, n0 = blockIdx.y * 128;

  __shared__ char sm[(PIPE ? 2 : 1) * 32768];  // per buffer: A 16KB + B 16KB

  f32x4 acc[4][4] = {};

  // staging: each global_load_lds writes 64 lanes * 16B = 1KB = 8 rows of 64 bf16.
  // LDS linear; source column pre-swizzled so ds_read uses byte^((row&7)<<4).
  const int rowInCh = l >> 3;
  const int colOff = 8 * ((l & 7) ^ (rowInCh & 7));

  const __hip_bfloat16* gAr[4];
  const __hip_bfloat16* gBr[4];
#pragma unroll
  for (int r = 0; r < 4; ++r) {
    gAr[r] = A + (size_t)(m0 + w * 32 + r * 8 + rowInCh) * lda + colOff;
    gBr[r] = B + (size_t)(n0 + w * 32 + r * 8 + rowInCh) * ldb + colOff;
  }

  auto stage = [&](int kt, int buf) {
    char* sA = sm + buf * 32768;
    char* sB = sA + 16384;
    const int ko = kt * 64;
#pragma unroll
    for (int r = 0; r < 4; ++r) {
      const int ch = w * 4 + r;
      gload16(gAr[r] + ko, sA + ch * 1024);
      gload16(gBr[r] + ko, sB + ch * 1024);
    }
  };

  auto compute = [&](int buf) {
    char* sA = sm + buf * 32768;
    char* sB = sA + 16384;
#pragma unroll
    for (int kk = 0; kk < 2; ++kk) {
      short8_t af[4], bf[4];
#pragma unroll
      for (int m = 0; m < 4; ++m) {
        const int row = wr * 64 + m * 16 + llo;
        const int inner = ((kk * 4 + lhi) ^ (row & 7)) * 16;
        af[m] = *(const short8_t*)(sA + row * 128 + inner);
      }
#pragma unroll
      for (int n = 0; n < 4; ++n) {
        const int row = wc * 64 + n * 16 + llo;
        const int inner = ((kk * 4 + lhi) ^ (row & 7)) * 16;
        bf[n] = *(const short8_t*)(sB + row * 128 + inner);
      }
#pragma unroll
      for (int m = 0; m < 4; ++m)
#pragma unroll
        for (int n = 0; n < 4; ++n)
          acc[m][n] = __builtin_amdgcn_mfma_f32_16x16x32_bf16(af[m], bf[n], acc[m][n], 0, 0, 0);
    }
  };

  const int nkt = K >> 6;
  if (PIPE) {
    stage(0, 0);
    __syncthreads();  // vmcnt(0) implied before barrier
    int cur = 0;
    for (int kt = 0; kt < nkt; ++kt) {
      if (kt + 1 < nkt) stage(kt + 1, cur ^ 1);  // prefetch hides under compute
      compute(cur);
      __syncthreads();  // drains prefetch vmcnt + protects buf reuse
      cur ^= 1;
    }
  } else {
    for (int kt = 0; kt < nkt; ++kt) {
      __syncthreads();
      stage(kt, 0);
      __syncthreads();
      compute(0);
    }
  }

  // epilogue: C/D layout col=lane&15, row=(lane>>4)*4+reg  [m89-verified]
#pragma unroll
  for (int m = 0; m < 4; ++m) {
#pragma unroll
    for (int r = 0; r < 4; ++r) {
      const int grow = m0 + wr * 64 + m * 16 + lhi * 4 + r;
#pragma unroll
      for (int n = 0; n < 4; ++n) {
        const int gcol = n0 + wc * 64 + n * 16 + llo;
        float v = acc[m][n][r] * scale;
        if (BIASMODE == 1) v += bias[grow];
        if (BIASMODE == 2) v += bias[gcol];
        const size_t idx = (size_t)z * strC + (size_t)grow * ldc + gcol;
        if (RESID) v += resid[(size_t)z * strR + (size_t)grow * ldc + gcol];
        if (OUTF == 0) ((__hip_bfloat16*)Cv)[idx] = __float2bfloat16(v);
        else           ((float*)Cv)[idx] = v;
      }
    }
  }
}

// ---------------------------------------------------------------------------
// GN stats stage A: partial sums. grid (32 groups, 16 slices, 2 z), 256 thr.
// ---------------------------------------------------------------------------
__global__ __launch_bounds__(256)
void gn_partial(const float* __restrict__ x, float* __restrict__ part)
{
  const int g = blockIdx.x, sl = blockIdx.y, z = blockIdx.z;
  const int tid = threadIdx.x;
  const float* xf = x + (size_t)z * 512 * 4096 + (size_t)g * 16 * 4096 + (size_t)sl * 4096;
  const float4* px = reinterpret_cast<const float4*>(xf);
  float s = 0.f, q = 0.f;
#pragma unroll
  for (int i = 0; i < 4; ++i) {
    float4 v = px[tid + i * 256];
    s += v.x + v.y + v.z + v.w;
    q += v.x * v.x + v.y * v.y + v.z * v.z + v.w * v.w;
  }
#pragma unroll
  for (int o = 32; o; o >>= 1) { s += __shfl_xor(s, o); q += __shfl_xor(q, o); }
  __shared__ float rs[4], rq[4];
  if ((tid & 63) == 0) { rs[tid >> 6] = s; rq[tid >> 6] = q; }
  __syncthreads();
  if (tid == 0) {
    s = rs[0] + rs[1] + rs[2] + rs[3];
    q = rq[0] + rq[1] + rq[2] + rq[3];
    part[(((size_t)z * 32 + g) * 16 + sl) * 2 + 0] = s;
    part[(((size_t)z * 32 + g) * 16 + sl) * 2 + 1] = q;
  }
}

__global__ __launch_bounds__(64)
void gn_finalize(const float* __restrict__ part, float* __restrict__ stats, int n)
{
  const int i = threadIdx.x;
  if (i >= n) return;
  float s = 0.f, q = 0.f;
#pragma unroll
  for (int sl = 0; sl < 16; ++sl) {
    s += part[(i * 16 + sl) * 2 + 0];
    q += part[(i * 16 + sl) * 2 + 1];
  }
  const float mean = s * (1.0f / 65536.0f);
  const float var = q * (1.0f / 65536.0f) - mean * mean;
  stats[i * 2 + 0] = mean;
  stats[i * 2 + 1] = rsqrtf(var + 1e-6f);
}

// ---------------------------------------------------------------------------
// Normalize + transpose: x[z][c][s] f32 -> ht[z][s][c] bf16 (64x64 LDS tiles)
// ---------------------------------------------------------------------------
__global__ __launch_bounds__(256)
void gn_apply_t(const float* __restrict__ x, const float* __restrict__ stats,
                const float* __restrict__ gns, const float* __restrict__ gnb,
                __hip_bfloat16* __restrict__ ht)
{
  const int st = blockIdx.x, ct = blockIdx.y, z = blockIdx.z;
  const int tid = threadIdx.x;
  __shared__ float tile[64][65];
  const float* xb = x + (size_t)z * 512 * 4096;
  const int lane64 = tid & 63, rr = tid >> 6;
#pragma unroll
  for (int pp = 0; pp < 16; ++pp) {
    const int cl = pp * 4 + rr;
    const int c = ct * 64 + cl;
    const int g = c >> 4;
    const float mean = stats[(z * 32 + g) * 2 + 0];
    const float rstd = stats[(z * 32 + g) * 2 + 1];
    const float val = xb[(size_t)c * 4096 + st * 64 + lane64];
    tile[cl][lane64] = (val - mean) * rstd * gns[c] + gnb[c];
  }
  __syncthreads();
  __hip_bfloat16* hb = ht + (size_t)z * 4096 * 512;
#pragma unroll
  for (int pp = 0; pp < 16; ++pp) {
    const int sl = pp * 4 + rr;
    const int s = st * 64 + sl;
    hb[(size_t)s * 512 + ct * 64 + lane64] = __float2bfloat16(tile[lane64][sl]);
  }
}

// ---------------------------------------------------------------------------
// In-place row softmax over 4096 bf16. 256 thr x 16 elems.
// ---------------------------------------------------------------------------
__global__ __launch_bounds__(256)
void softmax_rows(__hip_bfloat16* __restrict__ S, long long strZ)
{
  const int row = blockIdx.x, z = blockIdx.y;
  __hip_bfloat16* p = S + (size_t)z * strZ + (size_t)row * 4096;
  const int tid = threadIdx.x;
  short8_t a = *(const short8_t*)(p + tid * 16);
  short8_t b = *(const short8_t*)(p + tid * 16 + 8);
  float v[16];
#pragma unroll
  for (int i = 0; i < 8; ++i) { v[i] = bfbits2f(a[i]); v[8 + i] = bfbits2f(b[i]); }
  float m = v[0];
#pragma unroll
  for (int i = 1; i < 16; ++i) m = fmaxf(m, v[i]);
#pragma unroll
  for (int o = 32; o; o >>= 1) m = fmaxf(m, __shfl_xor(m, o));
  __shared__ float red[8];
  if ((tid & 63) == 0) red[tid >> 6] = m;
  __syncthreads();
  m = fmaxf(fmaxf(red[0], red[1]), fmaxf(red[2], red[3]));
  float s = 0.f;
#pragma unroll
  for (int i = 0; i < 16; ++i) { v[i] = exp2f((v[i] - m) * 1.44269504f); s += v[i]; }
#pragma unroll
  for (int o = 32; o; o >>= 1) s += __shfl_xor(s, o);
  __syncthreads();
  if ((tid & 63) == 0) red[4 + (tid >> 6)] = s;
  __syncthreads();
  s = red[4] + red[5] + red[6] + red[7];
  const float inv = 1.f / s;
#pragma unroll
  for (int i = 0; i < 8; ++i) { a[i] = f2bf_bits(v[i] * inv); b[i] = f2bf_bits(v[8 + i] * inv); }
  *(short8_t*)(p + tid * 16) = a;
  *(short8_t*)(p + tid * 16 + 8) = b;
}

// Straight casts: wq -> slot0, wk -> slot1, wo -> slot2. grid (256, 3).
__global__ __launch_bounds__(256)
void cast3(const float* __restrict__ w0, const float* __restrict__ w1,
           const float* __restrict__ w2, __hip_bfloat16* __restrict__ out)
{
  const int j = blockIdx.y;
  const float* src = (j == 0) ? w0 : (j == 1) ? w1 : w2;
  const int i = blockIdx.x * 256 + threadIdx.x;  // float4 index < 65536
  float4 v = reinterpret_cast<const float4*>(src)[i];
  short4_t o;
  o[0] = f2bf_bits(v.x); o[1] = f2bf_bits(v.y);
  o[2] = f2bf_bits(v.z); o[3] = f2bf_bits(v.w);
  *reinterpret_cast<short4_t*>((short*)out + (size_t)j * 262144 + (size_t)i * 4) = o;
}

// wv [c][i] f32 -> wvT [i][c] bf16. grid (8, 8) 64x64 tiles.
__global__ __launch_bounds__(256)
void transpose_cast(const float* __restrict__ w, __hip_bfloat16* __restrict__ wt)
{
  __shared__ float tile[64][65];
  const int ct = blockIdx.x, it = blockIdx.y;
  const int tid = threadIdx.x;
  const int lane = tid & 63, rr = tid >> 6;
#pragma unroll
  for (int p = 0; p < 16; ++p) {
    const int cl = p * 4 + rr;
    tile[cl][lane] = w[(size_t)(ct * 64 + cl) * 512 + it * 64 + lane];
  }
  __syncthreads();
#pragma unroll
  for (int p = 0; p < 16; ++p) {
    const int il = p * 4 + rr;
    wt[(size_t)(it * 64 + il) * 512 + ct * 64 + lane] = __float2bfloat16(tile[lane][il]);
  }
}

// bvo[o] = bo[o] + wo[o,:].bv ; bqk = [bq ; bk]. grid(8) x 64.
__global__ __launch_bounds__(64)
void prep_bias(const float* __restrict__ wo, const float* __restrict__ bv,
               const float* __restrict__ bo, const float* __restrict__ bq,
               const float* __restrict__ bk,
               float* __restrict__ bvo, float* __restrict__ bqk)
{
  const int o = blockIdx.x * 64 + threadIdx.x;
  const float4* row = reinterpret_cast<const float4*>(wo + (size_t)o * 512);
  const float4* b4 = reinterpret_cast<const float4*>(bv);
  float s = 0.f;
#pragma unroll 8
  for (int i = 0; i < 128; ++i) {
    float4 a = row[i], b = b4[i];
    s += a.x * b.x + a.y * b.y + a.z * b.z + a.w * b.w;
  }
  bvo[o] = s + bo[o];
  bqk[o] = bq[o];
  bqk[512 + o] = bk[o];
}

// ---------------------------------------------------------------------------
extern "C" void kernel_launch(void* const* d_in, const int* in_sizes, int n_in,
                              void* d_out, int out_size, void* d_ws, size_t ws_size,
                              hipStream_t stream)
{
  const float* x   = (const float*)d_in[0];
  const float* gns = (const float*)d_in[1];
  const float* gnb = (const float*)d_in[2];
  const float* wq  = (const float*)d_in[3];
  const float* bq  = (const float*)d_in[4];
  const float* wk  = (const float*)d_in[5];
  const float* bk  = (const float*)d_in[6];
  const float* wv  = (const float*)d_in[7];
  const float* bv  = (const float*)d_in[8];
  const float* wo  = (const float*)d_in[9];
  const float* bo  = (const float*)d_in[10];
  float* out = (float*)d_out;

  const int WB = 512 * 512;
  const long long HT  = 4096LL * 512;    // ht per-z elements
  const long long QKz = 4096LL * 1024;   // qk per-z elements
  const long long VOz = 512LL * 4096;    // vo per-z elements
  const long long SS  = 4096LL * 4096;   // S per-z elements
  const long long CHW = 512LL * 4096;

  char* base = (char*)d_ws;
  size_t off = 0;
  auto alloc = [&](size_t b) { void* r = base + off; off = (off + b + 255) & ~(size_t)255; return r; };

  // weights: [0]=wq, [1]=wk (wqk contiguous), [2]=wo, [3]=wvT, [4]=WVO
  __hip_bfloat16* wbf = (__hip_bfloat16*)alloc((size_t)5 * WB * 2);
  float* bqk   = (float*)alloc(1024 * 4);
  float* bvo   = (float*)alloc(512 * 4);
  float* part  = (float*)alloc(2 * 32 * 16 * 2 * 4);
  float* stats = (float*)alloc(2 * 32 * 2 * 4);
  const size_t fixed = off;

  const size_t qkB = (size_t)2 * QKz * 2;   // 16 MB
  const size_t voB = (size_t)2 * VOz * 2;   // 8 MB
  const size_t sB2 = (size_t)2 * SS * 2;    // 64 MB
  const size_t sB1 = (size_t)SS * 2;        // 32 MB
  const int MODE = (ws_size >= fixed + qkB + voB + sB2) ? 2 : 1;

  __hip_bfloat16* qk   = (__hip_bfloat16*)alloc(qkB);
  __hip_bfloat16* vo   = (__hip_bfloat16*)alloc(voB);
  const size_t sbufB = (MODE == 2) ? sB2 : sB1;
  __hip_bfloat16* sbuf = (__hip_bfloat16*)alloc(sbufB);
  // ht aliases the tail of sbuf: dead before S GEMM writes sbuf.
  __hip_bfloat16* ht = (__hip_bfloat16*)((char*)sbuf + sbufB - (size_t)2 * HT * 2);

  __hip_bfloat16* wqk = wbf;
  __hip_bfloat16* woB = wbf + 2 * WB;
  __hip_bfloat16* wvT = wbf + 3 * WB;
  __hip_bfloat16* wvo = wbf + 4 * WB;

  const float SC = 0.04419417382415922f;  // 512^-0.5

  cast3<<<dim3(256, 3), 256, 0, stream>>>(wq, wk, wo, wbf);
  transpose_cast<<<dim3(8, 8), 256, 0, stream>>>(wv, wvT);
  prep_bias<<<8, 64, 0, stream>>>(wo, bv, bo, bq, bk, bvo, bqk);
  gn_partial<<<dim3(32, 16, 2), 256, 0, stream>>>(x, part);
  gn_finalize<<<1, 64, 0, stream>>>(part, stats, 64);

  // WVO[o][i] = sum_c wo[o][c] * wvT[i][c]
  gemm_nt<0, 0, 0, 1><<<dim3(4, 4, 1), 256, 0, stream>>>(
      woB, wvT, wvo, nullptr, nullptr, 1.f, 512, 512, 512,
      512, 512, 512, 0, 0, 0, 0);

  gn_apply_t<<<dim3(64, 8, 2), 256, 0, stream>>>(x, stats, gns, gnb, ht);

  // [Q|K][s][o2] = ht . wqk^T + bqk  (o2 in 0..1024)
  gemm_nt<0, 2, 0, 1><<<dim3(32, 8, 2), 256, 0, stream>>>(
      ht, wqk, qk, bqk, nullptr, 1.f, 4096, 1024, 512,
      512, 512, 1024, HT, 0, QKz, 0);

  // VO[o][j] = WVO . ht^T
  gemm_nt<0, 0, 0, 1><<<dim3(4, 32, 2), 256, 0, stream>>>(
      wvo, ht, vo, nullptr, nullptr, 1.f, 512, 4096, 512,
      512, 512, 4096, 0, HT, VOz, 0);

  if (MODE == 2) {
    // S[i][j] = (Q . K^T) * scale
    gemm_nt<0, 0, 0, 0><<<dim3(32, 32, 2), 256, 0, stream>>>(
        qk, qk + 512, sbuf, nullptr, nullptr, SC, 4096, 4096, 512,
        1024, 1024, 4096, QKz, QKz, SS, 0);
    softmax_rows<<<dim3(4096, 2), 256, 0, stream>>>(sbuf, SS);
    // out[o][i] = sum_j VO[o][j] P[i][j] + bvo[o] + x[o][i]
    gemm_nt<1, 1, 1, 1><<<dim3(4, 32, 2), 256, 0, stream>>>(
        vo, sbuf, out, bvo, x, 1.f, 512, 4096, 4096,
        4096, 4096, 4096, VOz, SS, CHW, CHW);
  } else {
    for (int z = 0; z < 2; ++z) {
      gemm_nt<0, 0, 0, 0><<<dim3(32, 32, 1), 256, 0, stream>>>(
          qk + (size_t)z * QKz, qk + (size_t)z * QKz + 512, sbuf, nullptr, nullptr,
          SC, 4096, 4096, 512, 1024, 1024, 4096, 0, 0, 0, 0);
      softmax_rows<<<dim3(4096, 1), 256, 0, stream>>>(sbuf, 0);
      gemm_nt<1, 1, 1, 1><<<dim3(4, 32, 1), 256, 0, stream>>>(
          vo + (size_t)z * VOz, sbuf, out + (size_t)z * CHW, bvo, x + (size_t)z * CHW,
          1.f, 512, 4096, 4096, 4096, 4096, 4096, 0, 0, 0, 0);
    }
  }
}

// Round 4
// 172.770 us; speedup vs baseline: 1.4897x; 1.0290x over previous
//
#include <hip/hip_runtime.h>
#include <hip/hip_bf16.h>

// AttnBlock: GN -> QKV 1x1conv -> attention(n=4096,d=512) -> out-proj -> +x
// R4: XCD-aware block swizzles (T1) so blocks sharing operand panels are
// co-resident on one XCD's L2: SWZ=1 for PV/VO (4 m-blocks per S-panel on
// same XCD), SWZ=2 for S GEMM (8m x 16n region per XCD, 3MB < 4MB L2).

typedef __attribute__((ext_vector_type(8))) short short8_t;
typedef __attribute__((ext_vector_type(4))) short short4_t;
typedef __attribute__((ext_vector_type(4))) float f32x4;

__device__ __forceinline__ void gload16(const void* g, void* l) {
  __builtin_amdgcn_global_load_lds(
      (const __attribute__((address_space(1))) void*)g,
      (__attribute__((address_space(3))) void*)l, 16, 0, 0);
}

__device__ __forceinline__ short f2bf_bits(float f) {
  __hip_bfloat16 h = __float2bfloat16(f);
  return *reinterpret_cast<short*>(&h);
}
__device__ __forceinline__ float bfbits2f(short s) {
  union { unsigned int u; float f; } c;
  c.u = ((unsigned int)(unsigned short)s) << 16;
  return c.f;
}

// ---------------------------------------------------------------------------
// NT GEMM: C[m][n] = scale * sum_k A[m][k]*B[n][k] (+bias)(+resid)
// A rows at lda, B rows at ldb (both bf16, K-contiguous). M,N mult 128, K of 64.
// OUTF: 0 bf16 out, 1 f32 out. BIASMODE: 0 none, 1 per-row(m), 2 per-col(n).
// PIPE: 1 = double-buffered prefetch (64KB LDS), 0 = serial (32KB LDS).
// SWZ: 0 = blockIdx 3D direct. 1 = flat 256 (geometry 4m x 32n x 2z): 4
//   m-blocks sharing a B panel on one XCD (xcd = b&7). 2 = flat 2048
//   (32m x 32n x 2z): 8m x 16n region per XCD per z.
// ---------------------------------------------------------------------------
template<int OUTF, int BIASMODE, int RESID, int PIPE, int SWZ>
__global__ __launch_bounds__(256, 2)
void gemm_nt(const __hip_bfloat16* __restrict__ A,
             const __hip_bfloat16* __restrict__ B,
             void* __restrict__ Cv,
             const float* __restrict__ bias,
             const float* __restrict__ resid,
             float scale, int M, int N, int K,
             int lda, int ldb, int ldc,
             long long strA, long long strB, long long strC, long long strR)
{
  int bm, bn, bz;
  if (SWZ == 0) {
    bm = blockIdx.x; bn = blockIdx.y; bz = blockIdx.z;
  } else if (SWZ == 1) {
    const int b = blockIdx.x;            // 256 blocks
    const int xcd = b & 7, slot = b >> 3;
    const int panel = xcd * 8 + (slot >> 2);  // 0..63 = (z,n)
    bm = slot & 3; bn = panel & 31; bz = panel >> 5;
  } else {
    const int b = blockIdx.x;            // 2048 blocks
    bz = b >> 10;
    const int b2 = b & 1023;
    const int xcd = b2 & 7, s = b2 >> 3; // s 0..127
    bm = (xcd >> 1) * 8 + (s & 7);
    bn = (xcd & 1) * 16 + (s >> 3);
  }
  const int z = bz;
  A += (size_t)z * strA;
  B += (size_t)z * strB;

  const int tid = threadIdx.x;
  const int w = tid >> 6, l = tid & 63;
  const int wr = w >> 1, wc = w & 1;
  const int lhi = l >> 4, llo = l & 15;
  const int m0 = bm * 128, n0 = bn * 128;

  __shared__ char sm[(PIPE ? 2 : 1) * 32768];  // per buffer: A 16KB + B 16KB

  f32x4 acc[4][4] = {};

  // staging: each global_load_lds writes 64 lanes * 16B = 1KB = 8 rows of 64 bf16.
  // LDS linear; source column pre-swizzled so ds_read uses byte^((row&7)<<4).
  const int rowInCh = l >> 3;
  const int colOff = 8 * ((l & 7) ^ (rowInCh & 7));

  const __hip_bfloat16* gAr[4];
  const __hip_bfloat16* gBr[4];
#pragma unroll
  for (int r = 0; r < 4; ++r) {
    gAr[r] = A + (size_t)(m0 + w * 32 + r * 8 + rowInCh) * lda + colOff;
    gBr[r] = B + (size_t)(n0 + w * 32 + r * 8 + rowInCh) * ldb + colOff;
  }

  auto stage = [&](int kt, int buf) {
    char* sA = sm + buf * 32768;
    char* sB = sA + 16384;
    const int ko = kt * 64;
#pragma unroll
    for (int r = 0; r < 4; ++r) {
      const int ch = w * 4 + r;
      gload16(gAr[r] + ko, sA + ch * 1024);
      gload16(gBr[r] + ko, sB + ch * 1024);
    }
  };

  auto compute = [&](int buf) {
    char* sA = sm + buf * 32768;
    char* sB = sA + 16384;
#pragma unroll
    for (int kk = 0; kk < 2; ++kk) {
      short8_t af[4], bf[4];
#pragma unroll
      for (int m = 0; m < 4; ++m) {
        const int row = wr * 64 + m * 16 + llo;
        const int inner = ((kk * 4 + lhi) ^ (row & 7)) * 16;
        af[m] = *(const short8_t*)(sA + row * 128 + inner);
      }
#pragma unroll
      for (int n = 0; n < 4; ++n) {
        const int row = wc * 64 + n * 16 + llo;
        const int inner = ((kk * 4 + lhi) ^ (row & 7)) * 16;
        bf[n] = *(const short8_t*)(sB + row * 128 + inner);
      }
#pragma unroll
      for (int m = 0; m < 4; ++m)
#pragma unroll
        for (int n = 0; n < 4; ++n)
          acc[m][n] = __builtin_amdgcn_mfma_f32_16x16x32_bf16(af[m], bf[n], acc[m][n], 0, 0, 0);
    }
  };

  const int nkt = K >> 6;
  if (PIPE) {
    stage(0, 0);
    __syncthreads();
    int cur = 0;
    for (int kt = 0; kt < nkt; ++kt) {
      if (kt + 1 < nkt) stage(kt + 1, cur ^ 1);  // prefetch hides under compute
      compute(cur);
      __syncthreads();
      cur ^= 1;
    }
  } else {
    for (int kt = 0; kt < nkt; ++kt) {
      __syncthreads();
      stage(kt, 0);
      __syncthreads();
      compute(0);
    }
  }

  // epilogue: C/D layout col=lane&15, row=(lane>>4)*4+reg  [m89-verified]
#pragma unroll
  for (int m = 0; m < 4; ++m) {
#pragma unroll
    for (int r = 0; r < 4; ++r) {
      const int grow = m0 + wr * 64 + m * 16 + lhi * 4 + r;
#pragma unroll
      for (int n = 0; n < 4; ++n) {
        const int gcol = n0 + wc * 64 + n * 16 + llo;
        float v = acc[m][n][r] * scale;
        if (BIASMODE == 1) v += bias[grow];
        if (BIASMODE == 2) v += bias[gcol];
        const size_t idx = (size_t)z * strC + (size_t)grow * ldc + gcol;
        if (RESID) v += resid[(size_t)z * strR + (size_t)grow * ldc + gcol];
        if (OUTF == 0) ((__hip_bfloat16*)Cv)[idx] = __float2bfloat16(v);
        else           ((float*)Cv)[idx] = v;
      }
    }
  }
}

// ---------------------------------------------------------------------------
// GN stats stage A: partial sums. grid (32 groups, 16 slices, 2 z), 256 thr.
// ---------------------------------------------------------------------------
__global__ __launch_bounds__(256)
void gn_partial(const float* __restrict__ x, float* __restrict__ part)
{
  const int g = blockIdx.x, sl = blockIdx.y, z = blockIdx.z;
  const int tid = threadIdx.x;
  const float* xf = x + (size_t)z * 512 * 4096 + (size_t)g * 16 * 4096 + (size_t)sl * 4096;
  const float4* px = reinterpret_cast<const float4*>(xf);
  float s = 0.f, q = 0.f;
#pragma unroll
  for (int i = 0; i < 4; ++i) {
    float4 v = px[tid + i * 256];
    s += v.x + v.y + v.z + v.w;
    q += v.x * v.x + v.y * v.y + v.z * v.z + v.w * v.w;
  }
#pragma unroll
  for (int o = 32; o; o >>= 1) { s += __shfl_xor(s, o); q += __shfl_xor(q, o); }
  __shared__ float rs[4], rq[4];
  if ((tid & 63) == 0) { rs[tid >> 6] = s; rq[tid >> 6] = q; }
  __syncthreads();
  if (tid == 0) {
    s = rs[0] + rs[1] + rs[2] + rs[3];
    q = rq[0] + rq[1] + rq[2] + rq[3];
    part[(((size_t)z * 32 + g) * 16 + sl) * 2 + 0] = s;
    part[(((size_t)z * 32 + g) * 16 + sl) * 2 + 1] = q;
  }
}

__global__ __launch_bounds__(64)
void gn_finalize(const float* __restrict__ part, float* __restrict__ stats, int n)
{
  const int i = threadIdx.x;
  if (i >= n) return;
  float s = 0.f, q = 0.f;
#pragma unroll
  for (int sl = 0; sl < 16; ++sl) {
    s += part[(i * 16 + sl) * 2 + 0];
    q += part[(i * 16 + sl) * 2 + 1];
  }
  const float mean = s * (1.0f / 65536.0f);
  const float var = q * (1.0f / 65536.0f) - mean * mean;
  stats[i * 2 + 0] = mean;
  stats[i * 2 + 1] = rsqrtf(var + 1e-6f);
}

// ---------------------------------------------------------------------------
// Normalize + transpose: x[z][c][s] f32 -> ht[z][s][c] bf16 (64x64 LDS tiles)
// ---------------------------------------------------------------------------
__global__ __launch_bounds__(256)
void gn_apply_t(const float* __restrict__ x, const float* __restrict__ stats,
                const float* __restrict__ gns, const float* __restrict__ gnb,
                __hip_bfloat16* __restrict__ ht)
{
  const int st = blockIdx.x, ct = blockIdx.y, z = blockIdx.z;
  const int tid = threadIdx.x;
  __shared__ float tile[64][65];
  const float* xb = x + (size_t)z * 512 * 4096;
  const int lane64 = tid & 63, rr = tid >> 6;
#pragma unroll
  for (int pp = 0; pp < 16; ++pp) {
    const int cl = pp * 4 + rr;
    const int c = ct * 64 + cl;
    const int g = c >> 4;
    const float mean = stats[(z * 32 + g) * 2 + 0];
    const float rstd = stats[(z * 32 + g) * 2 + 1];
    const float val = xb[(size_t)c * 4096 + st * 64 + lane64];
    tile[cl][lane64] = (val - mean) * rstd * gns[c] + gnb[c];
  }
  __syncthreads();
  __hip_bfloat16* hb = ht + (size_t)z * 4096 * 512;
#pragma unroll
  for (int pp = 0; pp < 16; ++pp) {
    const int sl = pp * 4 + rr;
    const int s = st * 64 + sl;
    hb[(size_t)s * 512 + ct * 64 + lane64] = __float2bfloat16(tile[lane64][sl]);
  }
}

// ---------------------------------------------------------------------------
// In-place row softmax over 4096 bf16. 256 thr x 16 elems.
// ---------------------------------------------------------------------------
__global__ __launch_bounds__(256)
void softmax_rows(__hip_bfloat16* __restrict__ S, long long strZ)
{
  const int row = blockIdx.x, z = blockIdx.y;
  __hip_bfloat16* p = S + (size_t)z * strZ + (size_t)row * 4096;
  const int tid = threadIdx.x;
  short8_t a = *(const short8_t*)(p + tid * 16);
  short8_t b = *(const short8_t*)(p + tid * 16 + 8);
  float v[16];
#pragma unroll
  for (int i = 0; i < 8; ++i) { v[i] = bfbits2f(a[i]); v[8 + i] = bfbits2f(b[i]); }
  float m = v[0];
#pragma unroll
  for (int i = 1; i < 16; ++i) m = fmaxf(m, v[i]);
#pragma unroll
  for (int o = 32; o; o >>= 1) m = fmaxf(m, __shfl_xor(m, o));
  __shared__ float red[8];
  if ((tid & 63) == 0) red[tid >> 6] = m;
  __syncthreads();
  m = fmaxf(fmaxf(red[0], red[1]), fmaxf(red[2], red[3]));
  float s = 0.f;
#pragma unroll
  for (int i = 0; i < 16; ++i) { v[i] = exp2f((v[i] - m) * 1.44269504f); s += v[i]; }
#pragma unroll
  for (int o = 32; o; o >>= 1) s += __shfl_xor(s, o);
  __syncthreads();
  if ((tid & 63) == 0) red[4 + (tid >> 6)] = s;
  __syncthreads();
  s = red[4] + red[5] + red[6] + red[7];
  const float inv = 1.f / s;
#pragma unroll
  for (int i = 0; i < 8; ++i) { a[i] = f2bf_bits(v[i] * inv); b[i] = f2bf_bits(v[8 + i] * inv); }
  *(short8_t*)(p + tid * 16) = a;
  *(short8_t*)(p + tid * 16 + 8) = b;
}

// Straight casts: wq -> slot0, wk -> slot1, wo -> slot2. grid (256, 3).
__global__ __launch_bounds__(256)
void cast3(const float* __restrict__ w0, const float* __restrict__ w1,
           const float* __restrict__ w2, __hip_bfloat16* __restrict__ out)
{
  const int j = blockIdx.y;
  const float* src = (j == 0) ? w0 : (j == 1) ? w1 : w2;
  const int i = blockIdx.x * 256 + threadIdx.x;  // float4 index < 65536
  float4 v = reinterpret_cast<const float4*>(src)[i];
  short4_t o;
  o[0] = f2bf_bits(v.x); o[1] = f2bf_bits(v.y);
  o[2] = f2bf_bits(v.z); o[3] = f2bf_bits(v.w);
  *reinterpret_cast<short4_t*>((short*)out + (size_t)j * 262144 + (size_t)i * 4) = o;
}

// wv [c][i] f32 -> wvT [i][c] bf16. grid (8, 8) 64x64 tiles.
__global__ __launch_bounds__(256)
void transpose_cast(const float* __restrict__ w, __hip_bfloat16* __restrict__ wt)
{
  __shared__ float tile[64][65];
  const int ct = blockIdx.x, it = blockIdx.y;
  const int tid = threadIdx.x;
  const int lane = tid & 63, rr = tid >> 6;
#pragma unroll
  for (int p = 0; p < 16; ++p) {
    const int cl = p * 4 + rr;
    tile[cl][lane] = w[(size_t)(ct * 64 + cl) * 512 + it * 64 + lane];
  }
  __syncthreads();
#pragma unroll
  for (int p = 0; p < 16; ++p) {
    const int il = p * 4 + rr;
    wt[(size_t)(it * 64 + il) * 512 + ct * 64 + lane] = __float2bfloat16(tile[lane][il]);
  }
}

// bvo[o] = bo[o] + wo[o,:].bv ; bqk = [bq ; bk]. grid(8) x 64.
__global__ __launch_bounds__(64)
void prep_bias(const float* __restrict__ wo, const float* __restrict__ bv,
               const float* __restrict__ bo, const float* __restrict__ bq,
               const float* __restrict__ bk,
               float* __restrict__ bvo, float* __restrict__ bqk)
{
  const int o = blockIdx.x * 64 + threadIdx.x;
  const float4* row = reinterpret_cast<const float4*>(wo + (size_t)o * 512);
  const float4* b4 = reinterpret_cast<const float4*>(bv);
  float s = 0.f;
#pragma unroll 8
  for (int i = 0; i < 128; ++i) {
    float4 a = row[i], b = b4[i];
    s += a.x * b.x + a.y * b.y + a.z * b.z + a.w * b.w;
  }
  bvo[o] = s + bo[o];
  bqk[o] = bq[o];
  bqk[512 + o] = bk[o];
}

// ---------------------------------------------------------------------------
extern "C" void kernel_launch(void* const* d_in, const int* in_sizes, int n_in,
                              void* d_out, int out_size, void* d_ws, size_t ws_size,
                              hipStream_t stream)
{
  const float* x   = (const float*)d_in[0];
  const float* gns = (const float*)d_in[1];
  const float* gnb = (const float*)d_in[2];
  const float* wq  = (const float*)d_in[3];
  const float* bq  = (const float*)d_in[4];
  const float* wk  = (const float*)d_in[5];
  const float* bk  = (const float*)d_in[6];
  const float* wv  = (const float*)d_in[7];
  const float* bv  = (const float*)d_in[8];
  const float* wo  = (const float*)d_in[9];
  const float* bo  = (const float*)d_in[10];
  float* out = (float*)d_out;

  const int WB = 512 * 512;
  const long long HT  = 4096LL * 512;    // ht per-z elements
  const long long QKz = 4096LL * 1024;   // qk per-z elements
  const long long VOz = 512LL * 4096;    // vo per-z elements
  const long long SS  = 4096LL * 4096;   // S per-z elements
  const long long CHW = 512LL * 4096;

  char* base = (char*)d_ws;
  size_t off = 0;
  auto alloc = [&](size_t b) { void* r = base + off; off = (off + b + 255) & ~(size_t)255; return r; };

  // weights: [0]=wq, [1]=wk (wqk contiguous), [2]=wo, [3]=wvT, [4]=WVO
  __hip_bfloat16* wbf = (__hip_bfloat16*)alloc((size_t)5 * WB * 2);
  float* bqk   = (float*)alloc(1024 * 4);
  float* bvo   = (float*)alloc(512 * 4);
  float* part  = (float*)alloc(2 * 32 * 16 * 2 * 4);
  float* stats = (float*)alloc(2 * 32 * 2 * 4);
  const size_t fixed = off;

  const size_t qkB = (size_t)2 * QKz * 2;   // 16 MB
  const size_t voB = (size_t)2 * VOz * 2;   // 8 MB
  const size_t sB2 = (size_t)2 * SS * 2;    // 64 MB
  const size_t sB1 = (size_t)SS * 2;        // 32 MB
  const int MODE = (ws_size >= fixed + qkB + voB + sB2) ? 2 : 1;

  __hip_bfloat16* qk   = (__hip_bfloat16*)alloc(qkB);
  __hip_bfloat16* vo   = (__hip_bfloat16*)alloc(voB);
  const size_t sbufB = (MODE == 2) ? sB2 : sB1;
  __hip_bfloat16* sbuf = (__hip_bfloat16*)alloc(sbufB);
  // ht aliases the tail of sbuf: dead before S GEMM writes sbuf.
  __hip_bfloat16* ht = (__hip_bfloat16*)((char*)sbuf + sbufB - (size_t)2 * HT * 2);

  __hip_bfloat16* wqk = wbf;
  __hip_bfloat16* woB = wbf + 2 * WB;
  __hip_bfloat16* wvT = wbf + 3 * WB;
  __hip_bfloat16* wvo = wbf + 4 * WB;

  const float SC = 0.04419417382415922f;  // 512^-0.5

  cast3<<<dim3(256, 3), 256, 0, stream>>>(wq, wk, wo, wbf);
  transpose_cast<<<dim3(8, 8), 256, 0, stream>>>(wv, wvT);
  prep_bias<<<8, 64, 0, stream>>>(wo, bv, bo, bq, bk, bvo, bqk);
  gn_partial<<<dim3(32, 16, 2), 256, 0, stream>>>(x, part);
  gn_finalize<<<1, 64, 0, stream>>>(part, stats, 64);

  // WVO[o][i] = sum_c wo[o][c] * wvT[i][c]
  gemm_nt<0, 0, 0, 1, 0><<<dim3(4, 4, 1), 256, 0, stream>>>(
      woB, wvT, wvo, nullptr, nullptr, 1.f, 512, 512, 512,
      512, 512, 512, 0, 0, 0, 0);

  gn_apply_t<<<dim3(64, 8, 2), 256, 0, stream>>>(x, stats, gns, gnb, ht);

  // [Q|K][s][o2] = ht . wqk^T + bqk  (o2 in 0..1024)
  gemm_nt<0, 2, 0, 1, 0><<<dim3(32, 8, 2), 256, 0, stream>>>(
      ht, wqk, qk, bqk, nullptr, 1.f, 4096, 1024, 512,
      512, 512, 1024, HT, 0, QKz, 0);

  // VO[o][j] = WVO . ht^T   (flat 256, SWZ=1)
  gemm_nt<0, 0, 0, 1, 1><<<dim3(256, 1, 1), 256, 0, stream>>>(
      wvo, ht, vo, nullptr, nullptr, 1.f, 512, 4096, 512,
      512, 512, 4096, 0, HT, VOz, 0);

  if (MODE == 2) {
    // S[i][j] = (Q . K^T) * scale   (flat 2048, SWZ=2)
    gemm_nt<0, 0, 0, 0, 2><<<dim3(2048, 1, 1), 256, 0, stream>>>(
        qk, qk + 512, sbuf, nullptr, nullptr, SC, 4096, 4096, 512,
        1024, 1024, 4096, QKz, QKz, SS, 0);
    softmax_rows<<<dim3(4096, 2), 256, 0, stream>>>(sbuf, SS);
    // out[o][i] = sum_j VO[o][j] P[i][j] + bvo[o] + x[o][i]  (flat 256, SWZ=1)
    gemm_nt<1, 1, 1, 1, 1><<<dim3(256, 1, 1), 256, 0, stream>>>(
        vo, sbuf, out, bvo, x, 1.f, 512, 4096, 4096,
        4096, 4096, 4096, VOz, SS, CHW, CHW);
  } else {
    for (int z = 0; z < 2; ++z) {
      gemm_nt<0, 0, 0, 0, 0><<<dim3(32, 32, 1), 256, 0, stream>>>(
          qk + (size_t)z * QKz, qk + (size_t)z * QKz + 512, sbuf, nullptr, nullptr,
          SC, 4096, 4096, 512, 1024, 1024, 4096, 0, 0, 0, 0);
      softmax_rows<<<dim3(4096, 1), 256, 0, stream>>>(sbuf, 0);
      gemm_nt<1, 1, 1, 1, 0><<<dim3(4, 32, 1), 256, 0, stream>>>(
          vo + (size_t)z * VOz, sbuf, out + (size_t)z * CHW, bvo, x + (size_t)z * CHW,
          1.f, 512, 4096, 4096, 4096, 4096, 4096, 0, 0, 0, 0);
    }
  }
}

// Round 5
// 167.630 us; speedup vs baseline: 1.5353x; 1.0307x over previous
//
#include <hip/hip_runtime.h>
#include <hip/hip_bf16.h>

// AttnBlock: GN -> QKV 1x1conv -> attention(n=4096,d=512) -> out-proj -> +x
// R5: MF-templated tile height. MF=2 (64x128 tile) for the skinny M=512
// GEMMs (VO, PV) -> 512 blocks, 2-3 co-resident blocks/CU (was 1: lockstep
// 1 wave/SIMD, MfmaUtil 24%). SWZ=3 = bijective XCD map for 8m x 32n x 2z.

typedef __attribute__((ext_vector_type(8))) short short8_t;
typedef __attribute__((ext_vector_type(4))) short short4_t;
typedef __attribute__((ext_vector_type(4))) float f32x4;

__device__ __forceinline__ void gload16(const void* g, void* l) {
  __builtin_amdgcn_global_load_lds(
      (const __attribute__((address_space(1))) void*)g,
      (__attribute__((address_space(3))) void*)l, 16, 0, 0);
}

__device__ __forceinline__ short f2bf_bits(float f) {
  __hip_bfloat16 h = __float2bfloat16(f);
  return *reinterpret_cast<short*>(&h);
}
__device__ __forceinline__ float bfbits2f(short s) {
  union { unsigned int u; float f; } c;
  c.u = ((unsigned int)(unsigned short)s) << 16;
  return c.f;
}

// ---------------------------------------------------------------------------
// NT GEMM: C[m][n] = scale * sum_k A[m][k]*B[n][k] (+bias)(+resid)
// A rows at lda, B rows at ldb (both bf16, K-contiguous). Tile: (MF*32) x 128.
// M mult of MF*32, N mult 128, K mult 64.
// OUTF: 0 bf16 out, 1 f32 out. BIASMODE: 0 none, 1 per-row(m), 2 per-col(n).
// PIPE: 1 = double-buffered prefetch, 0 = serial.
// SWZ: 0 = blockIdx 3D direct.
//      2 = flat 2048 (32m x 32n x 2z): 8m x 16n region per XCD per z.
//      3 = flat 512 (8m x 32n x 2z, MF=2): all 8 m-blocks of a B-panel on
//          one XCD; 8 (n,z) panels per XCD.
// ---------------------------------------------------------------------------
template<int OUTF, int BIASMODE, int RESID, int PIPE, int SWZ, int MF>
__global__ __launch_bounds__(256, 2)
void gemm_nt(const __hip_bfloat16* __restrict__ A,
             const __hip_bfloat16* __restrict__ B,
             void* __restrict__ Cv,
             const float* __restrict__ bias,
             const float* __restrict__ resid,
             float scale, int M, int N, int K,
             int lda, int ldb, int ldc,
             long long strA, long long strB, long long strC, long long strR)
{
  int bm, bn, bz;
  if (SWZ == 0) {
    bm = blockIdx.x; bn = blockIdx.y; bz = blockIdx.z;
  } else if (SWZ == 2) {
    const int b = blockIdx.x;            // 2048 blocks
    bz = b >> 10;
    const int b2 = b & 1023;
    const int xcd = b2 & 7, s = b2 >> 3; // s 0..127
    bm = (xcd >> 1) * 8 + (s & 7);
    bn = (xcd & 1) * 16 + (s >> 3);
  } else {
    const int b = blockIdx.x;            // 512 blocks
    const int xcd = b & 7, slot = b >> 3;     // slot 0..63
    bm = slot & 7;
    const int panel = xcd * 8 + (slot >> 3);  // 0..63
    bn = panel & 31; bz = panel >> 5;
  }
  const int z = bz;
  A += (size_t)z * strA;
  B += (size_t)z * strB;

  const int tid = threadIdx.x;
  const int w = tid >> 6, l = tid & 63;
  const int wr = w >> 1, wc = w & 1;
  const int lhi = l >> 4, llo = l & 15;
  const int m0 = bm * (MF * 32), n0 = bn * 128;

  constexpr int BUFSZ = MF * 4096 + 16384;   // A tile + B tile bytes
  __shared__ char sm[(PIPE ? 2 : 1) * BUFSZ];

  f32x4 acc[MF][4] = {};

  // staging: each global_load_lds writes 64 lanes * 16B = 1KB = 8 rows of 64 bf16.
  // LDS linear; source column pre-swizzled so ds_read uses byte^((row&7)<<4).
  const int rowInCh = l >> 3;
  const int colOff = 8 * ((l & 7) ^ (rowInCh & 7));

  const __hip_bfloat16* gAr[MF];
  const __hip_bfloat16* gBr[4];
#pragma unroll
  for (int j = 0; j < MF; ++j)
    gAr[j] = A + (size_t)(m0 + w * (8 * MF) + j * 8 + rowInCh) * lda + colOff;
#pragma unroll
  for (int r = 0; r < 4; ++r)
    gBr[r] = B + (size_t)(n0 + w * 32 + r * 8 + rowInCh) * ldb + colOff;

  auto stage = [&](int kt, int buf) {
    char* sA = sm + buf * BUFSZ;
    char* sB = sA + MF * 4096;
    const int ko = kt * 64;
#pragma unroll
    for (int j = 0; j < MF; ++j)
      gload16(gAr[j] + ko, sA + (w * MF + j) * 1024);
#pragma unroll
    for (int r = 0; r < 4; ++r)
      gload16(gBr[r] + ko, sB + (w * 4 + r) * 1024);
  };

  auto compute = [&](int buf) {
    char* sA = sm + buf * BUFSZ;
    char* sB = sA + MF * 4096;
#pragma unroll
    for (int kk = 0; kk < 2; ++kk) {
      short8_t af[MF], bf[4];
#pragma unroll
      for (int m = 0; m < MF; ++m) {
        const int row = wr * (16 * MF) + m * 16 + llo;
        const int inner = ((kk * 4 + lhi) ^ (row & 7)) * 16;
        af[m] = *(const short8_t*)(sA + row * 128 + inner);
      }
#pragma unroll
      for (int n = 0; n < 4; ++n) {
        const int row = wc * 64 + n * 16 + llo;
        const int inner = ((kk * 4 + lhi) ^ (row & 7)) * 16;
        bf[n] = *(const short8_t*)(sB + row * 128 + inner);
      }
#pragma unroll
      for (int m = 0; m < MF; ++m)
#pragma unroll
        for (int n = 0; n < 4; ++n)
          acc[m][n] = __builtin_amdgcn_mfma_f32_16x16x32_bf16(af[m], bf[n], acc[m][n], 0, 0, 0);
    }
  };

  const int nkt = K >> 6;
  if (PIPE) {
    stage(0, 0);
    __syncthreads();
    int cur = 0;
    for (int kt = 0; kt < nkt; ++kt) {
      if (kt + 1 < nkt) stage(kt + 1, cur ^ 1);  // prefetch hides under compute
      compute(cur);
      __syncthreads();
      cur ^= 1;
    }
  } else {
    for (int kt = 0; kt < nkt; ++kt) {
      __syncthreads();
      stage(kt, 0);
      __syncthreads();
      compute(0);
    }
  }

  // epilogue: C/D layout col=lane&15, row=(lane>>4)*4+reg  [m89-verified]
#pragma unroll
  for (int m = 0; m < MF; ++m) {
#pragma unroll
    for (int r = 0; r < 4; ++r) {
      const int grow = m0 + wr * (16 * MF) + m * 16 + lhi * 4 + r;
#pragma unroll
      for (int n = 0; n < 4; ++n) {
        const int gcol = n0 + wc * 64 + n * 16 + llo;
        float v = acc[m][n][r] * scale;
        if (BIASMODE == 1) v += bias[grow];
        if (BIASMODE == 2) v += bias[gcol];
        const size_t idx = (size_t)z * strC + (size_t)grow * ldc + gcol;
        if (RESID) v += resid[(size_t)z * strR + (size_t)grow * ldc + gcol];
        if (OUTF == 0) ((__hip_bfloat16*)Cv)[idx] = __float2bfloat16(v);
        else           ((float*)Cv)[idx] = v;
      }
    }
  }
}

// ---------------------------------------------------------------------------
// GN stats stage A: partial sums. grid (32 groups, 16 slices, 2 z), 256 thr.
// ---------------------------------------------------------------------------
__global__ __launch_bounds__(256)
void gn_partial(const float* __restrict__ x, float* __restrict__ part)
{
  const int g = blockIdx.x, sl = blockIdx.y, z = blockIdx.z;
  const int tid = threadIdx.x;
  const float* xf = x + (size_t)z * 512 * 4096 + (size_t)g * 16 * 4096 + (size_t)sl * 4096;
  const float4* px = reinterpret_cast<const float4*>(xf);
  float s = 0.f, q = 0.f;
#pragma unroll
  for (int i = 0; i < 4; ++i) {
    float4 v = px[tid + i * 256];
    s += v.x + v.y + v.z + v.w;
    q += v.x * v.x + v.y * v.y + v.z * v.z + v.w * v.w;
  }
#pragma unroll
  for (int o = 32; o; o >>= 1) { s += __shfl_xor(s, o); q += __shfl_xor(q, o); }
  __shared__ float rs[4], rq[4];
  if ((tid & 63) == 0) { rs[tid >> 6] = s; rq[tid >> 6] = q; }
  __syncthreads();
  if (tid == 0) {
    s = rs[0] + rs[1] + rs[2] + rs[3];
    q = rq[0] + rq[1] + rq[2] + rq[3];
    part[(((size_t)z * 32 + g) * 16 + sl) * 2 + 0] = s;
    part[(((size_t)z * 32 + g) * 16 + sl) * 2 + 1] = q;
  }
}

__global__ __launch_bounds__(64)
void gn_finalize(const float* __restrict__ part, float* __restrict__ stats, int n)
{
  const int i = threadIdx.x;
  if (i >= n) return;
  float s = 0.f, q = 0.f;
#pragma unroll
  for (int sl = 0; sl < 16; ++sl) {
    s += part[(i * 16 + sl) * 2 + 0];
    q += part[(i * 16 + sl) * 2 + 1];
  }
  const float mean = s * (1.0f / 65536.0f);
  const float var = q * (1.0f / 65536.0f) - mean * mean;
  stats[i * 2 + 0] = mean;
  stats[i * 2 + 1] = rsqrtf(var + 1e-6f);
}

// ---------------------------------------------------------------------------
// Normalize + transpose: x[z][c][s] f32 -> ht[z][s][c] bf16 (64x64 LDS tiles)
// ---------------------------------------------------------------------------
__global__ __launch_bounds__(256)
void gn_apply_t(const float* __restrict__ x, const float* __restrict__ stats,
                const float* __restrict__ gns, const float* __restrict__ gnb,
                __hip_bfloat16* __restrict__ ht)
{
  const int st = blockIdx.x, ct = blockIdx.y, z = blockIdx.z;
  const int tid = threadIdx.x;
  __shared__ float tile[64][65];
  const float* xb = x + (size_t)z * 512 * 4096;
  const int lane64 = tid & 63, rr = tid >> 6;
#pragma unroll
  for (int pp = 0; pp < 16; ++pp) {
    const int cl = pp * 4 + rr;
    const int c = ct * 64 + cl;
    const int g = c >> 4;
    const float mean = stats[(z * 32 + g) * 2 + 0];
    const float rstd = stats[(z * 32 + g) * 2 + 1];
    const float val = xb[(size_t)c * 4096 + st * 64 + lane64];
    tile[cl][lane64] = (val - mean) * rstd * gns[c] + gnb[c];
  }
  __syncthreads();
  __hip_bfloat16* hb = ht + (size_t)z * 4096 * 512;
#pragma unroll
  for (int pp = 0; pp < 16; ++pp) {
    const int sl = pp * 4 + rr;
    const int s = st * 64 + sl;
    hb[(size_t)s * 512 + ct * 64 + lane64] = __float2bfloat16(tile[lane64][sl]);
  }
}

// ---------------------------------------------------------------------------
// In-place row softmax over 4096 bf16. 256 thr x 16 elems.
// ---------------------------------------------------------------------------
__global__ __launch_bounds__(256)
void softmax_rows(__hip_bfloat16* __restrict__ S, long long strZ)
{
  const int row = blockIdx.x, z = blockIdx.y;
  __hip_bfloat16* p = S + (size_t)z * strZ + (size_t)row * 4096;
  const int tid = threadIdx.x;
  short8_t a = *(const short8_t*)(p + tid * 16);
  short8_t b = *(const short8_t*)(p + tid * 16 + 8);
  float v[16];
#pragma unroll
  for (int i = 0; i < 8; ++i) { v[i] = bfbits2f(a[i]); v[8 + i] = bfbits2f(b[i]); }
  float m = v[0];
#pragma unroll
  for (int i = 1; i < 16; ++i) m = fmaxf(m, v[i]);
#pragma unroll
  for (int o = 32; o; o >>= 1) m = fmaxf(m, __shfl_xor(m, o));
  __shared__ float red[8];
  if ((tid & 63) == 0) red[tid >> 6] = m;
  __syncthreads();
  m = fmaxf(fmaxf(red[0], red[1]), fmaxf(red[2], red[3]));
  float s = 0.f;
#pragma unroll
  for (int i = 0; i < 16; ++i) { v[i] = exp2f((v[i] - m) * 1.44269504f); s += v[i]; }
#pragma unroll
  for (int o = 32; o; o >>= 1) s += __shfl_xor(s, o);
  __syncthreads();
  if ((tid & 63) == 0) red[4 + (tid >> 6)] = s;
  __syncthreads();
  s = red[4] + red[5] + red[6] + red[7];
  const float inv = 1.f / s;
#pragma unroll
  for (int i = 0; i < 8; ++i) { a[i] = f2bf_bits(v[i] * inv); b[i] = f2bf_bits(v[8 + i] * inv); }
  *(short8_t*)(p + tid * 16) = a;
  *(short8_t*)(p + tid * 16 + 8) = b;
}

// Straight casts: wq -> slot0, wk -> slot1, wo -> slot2. grid (256, 3).
__global__ __launch_bounds__(256)
void cast3(const float* __restrict__ w0, const float* __restrict__ w1,
           const float* __restrict__ w2, __hip_bfloat16* __restrict__ out)
{
  const int j = blockIdx.y;
  const float* src = (j == 0) ? w0 : (j == 1) ? w1 : w2;
  const int i = blockIdx.x * 256 + threadIdx.x;  // float4 index < 65536
  float4 v = reinterpret_cast<const float4*>(src)[i];
  short4_t o;
  o[0] = f2bf_bits(v.x); o[1] = f2bf_bits(v.y);
  o[2] = f2bf_bits(v.z); o[3] = f2bf_bits(v.w);
  *reinterpret_cast<short4_t*>((short*)out + (size_t)j * 262144 + (size_t)i * 4) = o;
}

// wv [c][i] f32 -> wvT [i][c] bf16. grid (8, 8) 64x64 tiles.
__global__ __launch_bounds__(256)
void transpose_cast(const float* __restrict__ w, __hip_bfloat16* __restrict__ wt)
{
  __shared__ float tile[64][65];
  const int ct = blockIdx.x, it = blockIdx.y;
  const int tid = threadIdx.x;
  const int lane = tid & 63, rr = tid >> 6;
#pragma unroll
  for (int p = 0; p < 16; ++p) {
    const int cl = p * 4 + rr;
    tile[cl][lane] = w[(size_t)(ct * 64 + cl) * 512 + it * 64 + lane];
  }
  __syncthreads();
#pragma unroll
  for (int p = 0; p < 16; ++p) {
    const int il = p * 4 + rr;
    wt[(size_t)(it * 64 + il) * 512 + ct * 64 + lane] = __float2bfloat16(tile[lane][il]);
  }
}

// bvo[o] = bo[o] + wo[o,:].bv ; bqk = [bq ; bk]. grid(8) x 64.
__global__ __launch_bounds__(64)
void prep_bias(const float* __restrict__ wo, const float* __restrict__ bv,
               const float* __restrict__ bo, const float* __restrict__ bq,
               const float* __restrict__ bk,
               float* __restrict__ bvo, float* __restrict__ bqk)
{
  const int o = blockIdx.x * 64 + threadIdx.x;
  const float4* row = reinterpret_cast<const float4*>(wo + (size_t)o * 512);
  const float4* b4 = reinterpret_cast<const float4*>(bv);
  float s = 0.f;
#pragma unroll 8
  for (int i = 0; i < 128; ++i) {
    float4 a = row[i], b = b4[i];
    s += a.x * b.x + a.y * b.y + a.z * b.z + a.w * b.w;
  }
  bvo[o] = s + bo[o];
  bqk[o] = bq[o];
  bqk[512 + o] = bk[o];
}

// ---------------------------------------------------------------------------
extern "C" void kernel_launch(void* const* d_in, const int* in_sizes, int n_in,
                              void* d_out, int out_size, void* d_ws, size_t ws_size,
                              hipStream_t stream)
{
  const float* x   = (const float*)d_in[0];
  const float* gns = (const float*)d_in[1];
  const float* gnb = (const float*)d_in[2];
  const float* wq  = (const float*)d_in[3];
  const float* bq  = (const float*)d_in[4];
  const float* wk  = (const float*)d_in[5];
  const float* bk  = (const float*)d_in[6];
  const float* wv  = (const float*)d_in[7];
  const float* bv  = (const float*)d_in[8];
  const float* wo  = (const float*)d_in[9];
  const float* bo  = (const float*)d_in[10];
  float* out = (float*)d_out;

  const int WB = 512 * 512;
  const long long HT  = 4096LL * 512;    // ht per-z elements
  const long long QKz = 4096LL * 1024;   // qk per-z elements
  const long long VOz = 512LL * 4096;    // vo per-z elements
  const long long SS  = 4096LL * 4096;   // S per-z elements
  const long long CHW = 512LL * 4096;

  char* base = (char*)d_ws;
  size_t off = 0;
  auto alloc = [&](size_t b) { void* r = base + off; off = (off + b + 255) & ~(size_t)255; return r; };

  // weights: [0]=wq, [1]=wk (wqk contiguous), [2]=wo, [3]=wvT, [4]=WVO
  __hip_bfloat16* wbf = (__hip_bfloat16*)alloc((size_t)5 * WB * 2);
  float* bqk   = (float*)alloc(1024 * 4);
  float* bvo   = (float*)alloc(512 * 4);
  float* part  = (float*)alloc(2 * 32 * 16 * 2 * 4);
  float* stats = (float*)alloc(2 * 32 * 2 * 4);
  const size_t fixed = off;

  const size_t qkB = (size_t)2 * QKz * 2;   // 16 MB
  const size_t voB = (size_t)2 * VOz * 2;   // 8 MB
  const size_t sB2 = (size_t)2 * SS * 2;    // 64 MB
  const size_t sB1 = (size_t)SS * 2;        // 32 MB
  const int MODE = (ws_size >= fixed + qkB + voB + sB2) ? 2 : 1;

  __hip_bfloat16* qk   = (__hip_bfloat16*)alloc(qkB);
  __hip_bfloat16* vo   = (__hip_bfloat16*)alloc(voB);
  const size_t sbufB = (MODE == 2) ? sB2 : sB1;
  __hip_bfloat16* sbuf = (__hip_bfloat16*)alloc(sbufB);
  // ht aliases the tail of sbuf: dead before S GEMM writes sbuf.
  __hip_bfloat16* ht = (__hip_bfloat16*)((char*)sbuf + sbufB - (size_t)2 * HT * 2);

  __hip_bfloat16* wqk = wbf;
  __hip_bfloat16* woB = wbf + 2 * WB;
  __hip_bfloat16* wvT = wbf + 3 * WB;
  __hip_bfloat16* wvo = wbf + 4 * WB;

  const float SC = 0.04419417382415922f;  // 512^-0.5

  cast3<<<dim3(256, 3), 256, 0, stream>>>(wq, wk, wo, wbf);
  transpose_cast<<<dim3(8, 8), 256, 0, stream>>>(wv, wvT);
  prep_bias<<<8, 64, 0, stream>>>(wo, bv, bo, bq, bk, bvo, bqk);
  gn_partial<<<dim3(32, 16, 2), 256, 0, stream>>>(x, part);
  gn_finalize<<<1, 64, 0, stream>>>(part, stats, 64);

  // WVO[o][i] = sum_c wo[o][c] * wvT[i][c]
  gemm_nt<0, 0, 0, 1, 0, 4><<<dim3(4, 4, 1), 256, 0, stream>>>(
      woB, wvT, wvo, nullptr, nullptr, 1.f, 512, 512, 512,
      512, 512, 512, 0, 0, 0, 0);

  gn_apply_t<<<dim3(64, 8, 2), 256, 0, stream>>>(x, stats, gns, gnb, ht);

  // [Q|K][s][o2] = ht . wqk^T + bqk  (o2 in 0..1024)
  gemm_nt<0, 2, 0, 1, 0, 4><<<dim3(32, 8, 2), 256, 0, stream>>>(
      ht, wqk, qk, bqk, nullptr, 1.f, 4096, 1024, 512,
      512, 512, 1024, HT, 0, QKz, 0);

  // VO[o][j] = WVO . ht^T   (64x128 tile, flat 512, SWZ=3)
  gemm_nt<0, 0, 0, 1, 3, 2><<<dim3(512, 1, 1), 256, 0, stream>>>(
      wvo, ht, vo, nullptr, nullptr, 1.f, 512, 4096, 512,
      512, 512, 4096, 0, HT, VOz, 0);

  if (MODE == 2) {
    // S[i][j] = (Q . K^T) * scale   (flat 2048, SWZ=2)
    gemm_nt<0, 0, 0, 0, 2, 4><<<dim3(2048, 1, 1), 256, 0, stream>>>(
        qk, qk + 512, sbuf, nullptr, nullptr, SC, 4096, 4096, 512,
        1024, 1024, 4096, QKz, QKz, SS, 0);
    softmax_rows<<<dim3(4096, 2), 256, 0, stream>>>(sbuf, SS);
    // out[o][i] = sum_j VO[o][j] P[i][j] + bvo[o] + x[o][i]  (64x128, SWZ=3)
    gemm_nt<1, 1, 1, 1, 3, 2><<<dim3(512, 1, 1), 256, 0, stream>>>(
        vo, sbuf, out, bvo, x, 1.f, 512, 4096, 4096,
        4096, 4096, 4096, VOz, SS, CHW, CHW);
  } else {
    for (int z = 0; z < 2; ++z) {
      gemm_nt<0, 0, 0, 0, 0, 4><<<dim3(32, 32, 1), 256, 0, stream>>>(
          qk + (size_t)z * QKz, qk + (size_t)z * QKz + 512, sbuf, nullptr, nullptr,
          SC, 4096, 4096, 512, 1024, 1024, 4096, 0, 0, 0, 0);
      softmax_rows<<<dim3(4096, 1), 256, 0, stream>>>(sbuf, 0);
      gemm_nt<1, 1, 1, 1, 0, 2><<<dim3(8, 32, 1), 256, 0, stream>>>(
          vo + (size_t)z * VOz, sbuf, out + (size_t)z * CHW, bvo, x + (size_t)z * CHW,
          1.f, 512, 4096, 4096, 4096, 4096, 4096, 0, 0, 0, 0);
    }
  }
}